// Round 3
// baseline (463.246 us; speedup 1.0000x reference)
//
#include <hip/hip_runtime.h>
#include <hip/hip_bf16.h>
#include <math.h>

// Problem constants (from reference)
#define T_TOK 8192            // B*S = 4*2048
#define HID   1024
#define NE    8
#define TOPKN 2
#define INTER 1408
#define NROWS (T_TOK*TOPKN)   // 16384 routed (token,expert) rows
#define MAXWL 144             // max 128-row worklist entries (gemm2)
#define MAXWL256 72           // max 256-row worklist entries (gemm1)
#define RBLK  256             // router blocks (32 tokens each)
#define GX1   (INTER/128)     // gemm1 grid.x = 11
#define GX2   (HID/128)       // gemm2 grid.x = 8

typedef __attribute__((ext_vector_type(8))) __bf16 bf16x8;
typedef __attribute__((ext_vector_type(4))) float f32x4;
typedef __attribute__((ext_vector_type(4))) unsigned int u32x4;

__device__ __forceinline__ unsigned short f2bf(float f) {
    unsigned int u = __builtin_bit_cast(unsigned int, f);
    unsigned int lsb = (u >> 16) & 1u;
    u += 0x7fffu + lsb;            // round-to-nearest-even
    return (unsigned short)(u >> 16);
}

// async global->LDS, 16B per lane (m97 pattern).
__device__ __forceinline__ void gl2lds16(const void* g, void* l) {
    __builtin_amdgcn_global_load_lds(
        (const __attribute__((address_space(1))) unsigned int*)g,
        (__attribute__((address_space(3))) unsigned int*)l, 16, 0, 0);
}

// ---------------------------------------------------------------- router
__global__ __launch_bounds__(256) void moe_router(
    const float* __restrict__ x, const float* __restrict__ gate_w,
    unsigned short* __restrict__ xb, float* __restrict__ logits_out,
    int* __restrict__ topk_idx, float* __restrict__ topk_w,
    int* __restrict__ hist_g)
{
    __shared__ int lh[NE];
    int tid = threadIdx.x, wave = tid >> 6, lane = tid & 63;
    if (tid < NE) lh[tid] = 0;
    __syncthreads();

#pragma unroll 1
    for (int i = 0; i < 8; i++) {
        int t = blockIdx.x * 32 + wave * 8 + i;
        const float4* xr = (const float4*)(x + (size_t)t * HID);
        float acc[NE];
#pragma unroll
        for (int e = 0; e < NE; e++) acc[e] = 0.f;
#pragma unroll
        for (int j = 0; j < 4; j++) {
            float4 xv = xr[j * 64 + lane];
            ushort4 pk;
            pk.x = f2bf(xv.x); pk.y = f2bf(xv.y);
            pk.z = f2bf(xv.z); pk.w = f2bf(xv.w);
            *(ushort4*)(xb + (size_t)t * HID + j * 256 + lane * 4) = pk;
#pragma unroll
            for (int e = 0; e < NE; e++) {
                float4 gv = *(const float4*)(gate_w + e * HID + j * 256 + lane * 4);
                acc[e] += xv.x * gv.x + xv.y * gv.y + xv.z * gv.z + xv.w * gv.w;
            }
        }
#pragma unroll
        for (int e = 0; e < NE; e++) {
            float v = acc[e];
#pragma unroll
            for (int off = 32; off; off >>= 1) v += __shfl_xor(v, off, 64);
            acc[e] = v;
        }
        if (lane == 0) {
            float m = acc[0];
#pragma unroll
            for (int e = 1; e < NE; e++) m = fmaxf(m, acc[e]);
            float p[NE]; float s = 0.f;
#pragma unroll
            for (int e = 0; e < NE; e++) { p[e] = expf(acc[e] - m); s += p[e]; }
            float inv = 1.f / s;
#pragma unroll
            for (int e = 0; e < NE; e++) logits_out[(size_t)t * NE + e] = acc[e];
            int i0 = 0;
#pragma unroll
            for (int e = 1; e < NE; e++) if (p[e] > p[i0]) i0 = e;
            int i1 = (i0 == 0) ? 1 : 0;
#pragma unroll
            for (int e = 0; e < NE; e++) if (e != i0 && p[e] > p[i1]) i1 = e;
            topk_idx[2 * t]     = i0; topk_w[2 * t]     = p[i0] * inv;
            topk_idx[2 * t + 1] = i1; topk_w[2 * t + 1] = p[i1] * inv;
            atomicAdd(&lh[i0], 1);
            atomicAdd(&lh[i1], 1);
        }
    }
    __syncthreads();
    if (tid < NE) hist_g[blockIdx.x * NE + tid] = lh[tid];
}

// ---------------------------------------------------------------- scan
__global__ __launch_bounds__(256) void moe_scan(
    const int* __restrict__ hist_g, int* __restrict__ offsets,
    int* __restrict__ block_base, int* __restrict__ wl, int* __restrict__ n_wl,
    int* __restrict__ wl256, int* __restrict__ n_wl256)
{
    __shared__ int h[RBLK * NE];
    __shared__ int cnt[NE], offs[NE];
    int tid = threadIdx.x;
    for (int i = tid; i < RBLK * NE; i += 256) h[i] = hist_g[i];
    __syncthreads();
    {
        int e = tid >> 5, g = tid & 31;
        int s = 0;
        for (int b = g; b < RBLK; b += 32) s += h[b * NE + e];
#pragma unroll
        for (int off2 = 16; off2; off2 >>= 1) s += __shfl_xor(s, off2, 32);
        if (g == 0) cnt[e] = s;
    }
    __syncthreads();
    if (tid == 0) {
        int s = 0;
        for (int e = 0; e < NE; e++) { offs[e] = s; offsets[e] = s; s += cnt[e]; }
        offsets[NE] = s;
        int n = 0;
        for (int e = 0; e < NE; e++)
            for (int r0 = 0; r0 < cnt[e]; r0 += 128)
                wl[n++] = (e << 24) | r0;
        *n_wl = n;
        int n2 = 0;
        for (int e = 0; e < NE; e++)
            for (int r0 = 0; r0 < cnt[e]; r0 += 256)
                wl256[n2++] = (e << 24) | r0;
        *n_wl256 = n2;
    }
    __syncthreads();
    if (tid < NE) {
        int run = offs[tid];
        for (int b = 0; b < RBLK; b++) {
            block_base[b * NE + tid] = run;
            run += h[b * NE + tid];
        }
    }
}

// ---------------------------------------------------------------- scatter
__global__ __launch_bounds__(64) void moe_scatter(
    const int* __restrict__ topk_idx, const float* __restrict__ topk_w,
    const int* __restrict__ block_base, int* __restrict__ row_token,
    float* __restrict__ row_w, int* __restrict__ tok_rows)
{
    __shared__ int base[NE];
    int tid = threadIdx.x;
    if (tid < NE) base[tid] = block_base[blockIdx.x * NE + tid];
    __syncthreads();
    int idx = blockIdx.x * 64 + tid;     // = 2*t + k
    int e = topk_idx[idx];
    int pos = atomicAdd(&base[e], 1);    // LDS atomic
    row_token[pos] = idx >> 1;
    row_w[pos] = topk_w[idx];
    tok_rows[idx] = pos;
}

// ---------------------------------------------------------------- transpose+cast
__global__ __launch_bounds__(256) void moe_transpose_cast(
    const float* __restrict__ in, unsigned short* __restrict__ out,
    int R_, int C_)
{
    __shared__ float tile[64][65];
    int e = blockIdx.z;
    const float* ine = in + (size_t)e * R_ * C_;
    unsigned short* oute = out + (size_t)e * R_ * C_;
    int c0 = blockIdx.x * 64, r0 = blockIdx.y * 64;
    int tid = threadIdx.x;
    int lr = tid >> 4;          // 0..15
    int lc = tid & 15;          // float4 column chunk
#pragma unroll
    for (int j = 0; j < 4; j++) {
        int r = lr + j * 16;
        float4 v = *(const float4*)(ine + (size_t)(r0 + r) * C_ + c0 + lc * 4);
        tile[r][lc * 4 + 0] = v.x; tile[r][lc * 4 + 1] = v.y;
        tile[r][lc * 4 + 2] = v.z; tile[r][lc * 4 + 3] = v.w;
    }
    __syncthreads();
#pragma unroll
    for (int j = 0; j < 4; j++) {
        int c = (tid >> 4) + j * 16;
        int r = (tid & 15) * 4;
        ushort4 pk;
        pk.x = f2bf(tile[r + 0][c]);
        pk.y = f2bf(tile[r + 1][c]);
        pk.z = f2bf(tile[r + 2][c]);
        pk.w = f2bf(tile[r + 3][c]);
        *(ushort4*)(oute + (size_t)(c0 + c) * R_ + r0 + r) = pk;
    }
}

// ---------------------------------------------------------------- grouped GEMM1
// 256x256 tile (256 routed rows x [128 gate-cols ++ 128 up-cols]), 512 threads
// (8 waves, 2M x 4N; per-wave 128x64). K-tile 64 split into two 32-K slices.
// Counted-vmcnt pipeline (T3+T4): 4 phases per K-tile; gate = s_waitcnt
// vmcnt(6) + s_barrier (6 = 2 loads/half-tile x 3 half-tiles in flight; a
// half staged at phase p is first read 4 gates later with exactly 6 same-wave
// loads issued after it -> induction-safe, never drains to 0 in the loop).
// XCD-chunked block swizzle: 11 x-blocks sharing an A-row-panel land on one
// XCD's L2 (792 blocks, 792%8==0 -> simple chunk remap is bijective).
__global__ __launch_bounds__(512, 2) void moe_gemm1(
    const unsigned short* __restrict__ xb,
    const unsigned short* __restrict__ wg_t,   // [NE][INTER][HID]
    const unsigned short* __restrict__ wu_t,   // [NE][INTER][HID]
    const int* __restrict__ offsets, const int* __restrict__ row_token,
    const int* __restrict__ wl, const int* __restrict__ n_wl,
    unsigned short* __restrict__ h_buf)        // [NROWS][INTER]
{
    // bijective XCD chunk swizzle (x fastest within a chunk)
    int lin = (int)(blockIdx.y * GX1 + blockIdx.x);
    const int chunk = (GX1 * MAXWL256) >> 3;           // 99
    int lin2 = (lin & 7) * chunk + (lin >> 3);
    int bx = lin2 % GX1, by = lin2 / GX1;

    if (by >= *n_wl) return;
    int wle = wl[by];
    int e = wle >> 24, row0 = wle & 0xffffff;
    int off = offsets[e], cnt = offsets[e + 1] - off;
    int i0 = bx * 128;

    __shared__ __align__(16) unsigned short As[32768];  // 64 KB: [2][2][256][32]
    __shared__ __align__(16) unsigned short Bs[32768];  // 64 KB

    int tid = threadIdx.x, wave = tid >> 6, lane = tid & 63;
    int wm = wave & 1, wn = wave >> 1;
    int l16 = lane & 15, quad = lane >> 4;
    int fsw = (l16 >> 1) & 3;                  // frag-read chunk xor

    // staging: lane l covers row rbase+(l>>2), phys chunk l&3; global k-chunk
    // = (l&3) ^ ((l>>3)&3), so LDS phys chunk c holds global chunk c^((r>>1)&3)
    int kswz = ((lane & 3) ^ ((lane >> 3) & 3)) * 8;
    int r0s = wave * 32 + (lane >> 2);         // staging row, load j=0
    int r1s = r0s + 16;                        // load j=1

    int gA0 = row0 + r0s, gA1 = row0 + r1s;
    int tok0 = row_token[off + ((gA0 < cnt) ? gA0 : 0)];
    int tok1 = row_token[off + ((gA1 < cnt) ? gA1 : 0)];
    const unsigned short* aptr0 = xb + (size_t)tok0 * HID + kswz;
    const unsigned short* aptr1 = xb + (size_t)tok1 * HID + kswz;

    int ic0 = i0 + (r0s >> 6) * 32 + (r0s & 31);
    int ic1 = i0 + (r1s >> 6) * 32 + (r1s & 31);
    const unsigned short* bptr0 =
        (((r0s >> 5) & 1) ? wu_t : wg_t) + (size_t)e * INTER * HID + (size_t)ic0 * HID + kswz;
    const unsigned short* bptr1 =
        (((r1s >> 5) & 1) ? wu_t : wg_t) + (size_t)e * INTER * HID + (size_t)ic1 * HID + kswz;

    f32x4 acc[8][4];
#pragma unroll
    for (int mi = 0; mi < 8; mi++)
#pragma unroll
        for (int ni = 0; ni < 4; ni++) acc[mi][ni] = {0.f, 0.f, 0.f, 0.f};

    // prologue: stage all 4 halves of K-tile 0 into buf 0, full drain once.
    {
        unsigned short* dA = &As[wave * 1024];
        unsigned short* dB = &Bs[wave * 1024];
        gl2lds16(aptr0, dA);            gl2lds16(aptr1, dA + 512);
        gl2lds16(bptr0, dB);            gl2lds16(bptr1, dB + 512);
        gl2lds16(aptr0 + 32, dA + 8192); gl2lds16(aptr1 + 32, dA + 8192 + 512);
        gl2lds16(bptr0 + 32, dB + 8192); gl2lds16(bptr1 + 32, dB + 8192 + 512);
    }
    __syncthreads();

#pragma unroll 1
    for (int kt = 0; kt < 16; kt++) {
        const unsigned short* Ac = &As[(kt & 1) << 14];
        const unsigned short* Bc = &Bs[(kt & 1) << 14];
        unsigned short* An = &As[(((kt + 1) & 1) << 14) + wave * 1024];
        unsigned short* Bn = &Bs[(((kt + 1) & 1) << 14) + wave * 1024];
        int kb = (kt + 1) * 64;
        bool more = kt < 15;
        bf16x8 a[8], b0, b1;

        // ---------- phase 1: slice 0, ni 0-1; stage A-ks0(kt+1)
        asm volatile("s_waitcnt vmcnt(6)" ::: "memory");
        __builtin_amdgcn_s_barrier();
#pragma unroll
        for (int mi = 0; mi < 8; mi++)
            a[mi] = *(const bf16x8*)&Ac[(wm * 128 + mi * 16 + l16) * 32 + (quad ^ fsw) * 8];
        b0 = *(const bf16x8*)&Bc[(wn * 64 + l16) * 32 + (quad ^ fsw) * 8];
        b1 = *(const bf16x8*)&Bc[(wn * 64 + 16 + l16) * 32 + (quad ^ fsw) * 8];
        if (more) { gl2lds16(aptr0 + kb, An); gl2lds16(aptr1 + kb, An + 512); }
        __builtin_amdgcn_s_setprio(1);
#pragma unroll
        for (int mi = 0; mi < 8; mi++) {
            acc[mi][0] = __builtin_amdgcn_mfma_f32_16x16x32_bf16(a[mi], b0, acc[mi][0], 0, 0, 0);
            acc[mi][1] = __builtin_amdgcn_mfma_f32_16x16x32_bf16(a[mi], b1, acc[mi][1], 0, 0, 0);
        }
        __builtin_amdgcn_s_setprio(0);

        // ---------- phase 2: slice 0, ni 2-3; stage B-ks0(kt+1)
        asm volatile("s_waitcnt vmcnt(6)" ::: "memory");
        __builtin_amdgcn_s_barrier();
        b0 = *(const bf16x8*)&Bc[(wn * 64 + 32 + l16) * 32 + (quad ^ fsw) * 8];
        b1 = *(const bf16x8*)&Bc[(wn * 64 + 48 + l16) * 32 + (quad ^ fsw) * 8];
        if (more) { gl2lds16(bptr0 + kb, Bn); gl2lds16(bptr1 + kb, Bn + 512); }
        __builtin_amdgcn_s_setprio(1);
#pragma unroll
        for (int mi = 0; mi < 8; mi++) {
            acc[mi][2] = __builtin_amdgcn_mfma_f32_16x16x32_bf16(a[mi], b0, acc[mi][2], 0, 0, 0);
            acc[mi][3] = __builtin_amdgcn_mfma_f32_16x16x32_bf16(a[mi], b1, acc[mi][3], 0, 0, 0);
        }
        __builtin_amdgcn_s_setprio(0);

        // ---------- phase 3: slice 1, ni 0-1; stage A-ks1(kt+1)
        asm volatile("s_waitcnt vmcnt(6)" ::: "memory");
        __builtin_amdgcn_s_barrier();
#pragma unroll
        for (int mi = 0; mi < 8; mi++)
            a[mi] = *(const bf16x8*)&Ac[8192 + (wm * 128 + mi * 16 + l16) * 32 + (quad ^ fsw) * 8];
        b0 = *(const bf16x8*)&Bc[8192 + (wn * 64 + l16) * 32 + (quad ^ fsw) * 8];
        b1 = *(const bf16x8*)&Bc[8192 + (wn * 64 + 16 + l16) * 32 + (quad ^ fsw) * 8];
        if (more) { gl2lds16(aptr0 + kb + 32, An + 8192); gl2lds16(aptr1 + kb + 32, An + 8192 + 512); }
        __builtin_amdgcn_s_setprio(1);
#pragma unroll
        for (int mi = 0; mi < 8; mi++) {
            acc[mi][0] = __builtin_amdgcn_mfma_f32_16x16x32_bf16(a[mi], b0, acc[mi][0], 0, 0, 0);
            acc[mi][1] = __builtin_amdgcn_mfma_f32_16x16x32_bf16(a[mi], b1, acc[mi][1], 0, 0, 0);
        }
        __builtin_amdgcn_s_setprio(0);

        // ---------- phase 4: slice 1, ni 2-3; stage B-ks1(kt+1)
        asm volatile("s_waitcnt vmcnt(6)" ::: "memory");
        __builtin_amdgcn_s_barrier();
        b0 = *(const bf16x8*)&Bc[8192 + (wn * 64 + 32 + l16) * 32 + (quad ^ fsw) * 8];
        b1 = *(const bf16x8*)&Bc[8192 + (wn * 64 + 48 + l16) * 32 + (quad ^ fsw) * 8];
        if (more) { gl2lds16(bptr0 + kb + 32, Bn + 8192); gl2lds16(bptr1 + kb + 32, Bn + 8192 + 512); }
        __builtin_amdgcn_s_setprio(1);
#pragma unroll
        for (int mi = 0; mi < 8; mi++) {
            acc[mi][2] = __builtin_amdgcn_mfma_f32_16x16x32_bf16(a[mi], b0, acc[mi][2], 0, 0, 0);
            acc[mi][3] = __builtin_amdgcn_mfma_f32_16x16x32_bf16(a[mi], b1, acc[mi][3], 0, 0, 0);
        }
        __builtin_amdgcn_s_setprio(0);
    }

    // epilogue: silu(g)*u -> bf16  (C/D: col=lane&15, row=quad*4+reg)
#pragma unroll
    for (int mi = 0; mi < 8; mi++)
#pragma unroll
        for (int np = 0; np < 2; np++)
#pragma unroll
            for (int r = 0; r < 4; r++) {
                int ml = wm * 128 + mi * 16 + quad * 4 + r;
                int row = row0 + ml;
                if (row < cnt) {
                    float g = acc[mi][np][r], u = acc[mi][np + 2][r];
                    float hv = (g / (1.f + expf(-g))) * u;
                    h_buf[(size_t)(off + row) * INTER + i0 + wn * 32 + np * 16 + l16] = f2bf(hv);
                }
            }
}

// ---------------------------------------------------------------- grouped GEMM2
// m97-style 128x128, per-wave 64x64, XOR-swizzle staging, double-buffered.
// XCD-chunked swizzle: 8 x-blocks sharing an h_buf row-panel -> one XCD L2.
__global__ __launch_bounds__(256) void moe_gemm2(
    const unsigned short* __restrict__ h_buf,  // [NROWS][INTER]
    const unsigned short* __restrict__ wd_t,   // [NE][HID][INTER]
    const int* __restrict__ offsets, const float* __restrict__ row_w,
    const int* __restrict__ wl, const int* __restrict__ n_wl,
    unsigned short* __restrict__ y_buf)        // [NROWS][HID]
{
    int lin = (int)(blockIdx.y * GX2 + blockIdx.x);
    const int chunk = (GX2 * MAXWL) >> 3;              // 144
    int lin2 = (lin & 7) * chunk + (lin >> 3);
    int bx = lin2 % GX2, by = lin2 / GX2;

    if (by >= *n_wl) return;
    int wle = wl[by];
    int e = wle >> 24, row0 = wle & 0xffffff;
    int off = offsets[e], cnt = offsets[e + 1] - off;
    int h0 = bx * 128;

    __shared__ __align__(16) unsigned short As[2][128 * 64];  // 32 KB
    __shared__ __align__(16) unsigned short Bs[2][128 * 64];  // 32 KB

    int tid = threadIdx.x, wave = tid >> 6, lane = tid & 63;
    int wm = wave & 1, wn = wave >> 1;
    int l16 = lane & 15, quad = lane >> 4;
    int r_ = lane >> 3, c_ = lane & 7;
    int sw = l16 & 7;

    const unsigned short* asrc[4];
    const unsigned short* bsrc[4];
#pragma unroll
    for (int it = 0; it < 4; it++) {
        int rloc = it * 32 + wave * 8 + r_;
        int rg = row0 + rloc;
        asrc[it] = h_buf + (size_t)(off + ((rg < cnt) ? rg : 0)) * INTER + (c_ ^ (rloc & 7)) * 8;
        bsrc[it] = wd_t + (size_t)e * HID * INTER + (size_t)(h0 + rloc) * INTER + (c_ ^ (rloc & 7)) * 8;
    }

    f32x4 acc[4][4];
#pragma unroll
    for (int mi = 0; mi < 4; mi++)
#pragma unroll
        for (int ni = 0; ni < 4; ni++) acc[mi][ni] = {0.f, 0.f, 0.f, 0.f};

    auto stage = [&](unsigned short* asb, unsigned short* bsb, int k0) {
#pragma unroll
        for (int it = 0; it < 4; it++) {
            gl2lds16(asrc[it] + k0, asb + (it * 32 + wave * 8) * 64);
            gl2lds16(bsrc[it] + k0, bsb + (it * 32 + wave * 8) * 64);
        }
    };
    auto compute = [&](const unsigned short* asb, const unsigned short* bsb) {
#pragma unroll
        for (int kk8 = 0; kk8 < 8; kk8 += 4) {
            int q = kk8 + quad;
            int qs = (q ^ sw) * 8;
            bf16x8 a[4], b[4];
#pragma unroll
            for (int mi = 0; mi < 4; mi++)
                a[mi] = *(const bf16x8*)&asb[(wm * 64 + mi * 16 + l16) * 64 + qs];
#pragma unroll
            for (int ni = 0; ni < 4; ni++)
                b[ni] = *(const bf16x8*)&bsb[(wn * 64 + ni * 16 + l16) * 64 + qs];
#pragma unroll
            for (int mi = 0; mi < 4; mi++)
#pragma unroll
                for (int ni = 0; ni < 4; ni++)
                    acc[mi][ni] = __builtin_amdgcn_mfma_f32_16x16x32_bf16(a[mi], b[ni], acc[mi][ni], 0, 0, 0);
        }
    };

    // NK = INTER/64 = 22 K-tiles (even), unrolled by 2.
    stage(As[0], Bs[0], 0);
    __syncthreads();
#pragma unroll 1
    for (int t = 0; t < 22; t += 2) {
        stage(As[1], Bs[1], (t + 1) * 64);
        compute(As[0], Bs[0]);
        __syncthreads();
        if (t + 2 < 22) stage(As[0], Bs[0], (t + 2) * 64);
        compute(As[1], Bs[1]);
        __syncthreads();
    }

#pragma unroll
    for (int mi = 0; mi < 4; mi++)
#pragma unroll
        for (int ni = 0; ni < 4; ni++)
#pragma unroll
            for (int r = 0; r < 4; r++) {
                int ml = wm * 64 + mi * 16 + quad * 4 + r;
                int row = row0 + ml;
                if (row < cnt) {
                    float w = row_w[off + row];
                    y_buf[(size_t)(off + row) * HID + h0 + wn * 64 + ni * 16 + l16] =
                        f2bf(acc[mi][ni][r] * w);
                }
            }
}

// ---------------------------------------------------------------- combine
__global__ __launch_bounds__(256) void moe_combine(
    const unsigned short* __restrict__ y_buf, const int* __restrict__ tok_rows,
    float* __restrict__ out)
{
    int gid = blockIdx.x * 256 + threadIdx.x;   // T*H/8 threads
    int t = gid >> 7;
    int c = gid & 127;
    u32x4 a = *(const u32x4*)(y_buf + (size_t)tok_rows[2 * t]     * HID + c * 8);
    u32x4 b = *(const u32x4*)(y_buf + (size_t)tok_rows[2 * t + 1] * HID + c * 8);
    float res[8];
#pragma unroll
    for (int j = 0; j < 4; j++) {
        unsigned int wa = a[j], wb = b[j];
        res[2 * j]     = __builtin_bit_cast(float, wa << 16)
                       + __builtin_bit_cast(float, wb << 16);
        res[2 * j + 1] = __builtin_bit_cast(float, wa & 0xffff0000u)
                       + __builtin_bit_cast(float, wb & 0xffff0000u);
    }
    float* o = out + (size_t)t * HID + c * 8;
    *(float4*)(o)     = make_float4(res[0], res[1], res[2], res[3]);
    *(float4*)(o + 4) = make_float4(res[4], res[5], res[6], res[7]);
}

// ---------------------------------------------------------------- launch
extern "C" void kernel_launch(void* const* d_in, const int* in_sizes, int n_in,
                              void* d_out, int out_size, void* d_ws, size_t ws_size,
                              hipStream_t stream)
{
    const float* x      = (const float*)d_in[0];
    const float* gate_w = (const float*)d_in[1];
    const float* w_gate = (const float*)d_in[2];
    const float* w_up   = (const float*)d_in[3];
    const float* w_down = (const float*)d_in[4];
    float* out = (float*)d_out;                    // final [T,H] ++ logits [T,E]
    float* logits_out = out + (size_t)T_TOK * HID;

    char* ws = (char*)d_ws;
    int*   offsets    = (int*)(ws + 0);                  // 9 ints
    int*   n_wl       = (int*)(ws + 64);
    int*   n_wl256    = (int*)(ws + 68);
    int*   wl         = (int*)(ws + 128);                // MAXWL ints (576 B)
    int*   wl256      = (int*)(ws + 704);                // MAXWL256 ints (288 B)
    int*   hist_g     = (int*)(ws + 1024);               // RBLK*NE = 8 KB
    int*   block_base = (int*)(ws + 1024 + 8192);        // 8 KB
    int*   topk_idx   = (int*)(ws + 32768);                       // 64 KB
    float* topk_w     = (float*)(ws + 32768 + 65536);             // 64 KB
    int*   row_token  = (int*)(ws + 32768 + 2 * 65536);           // 64 KB
    float* row_w      = (float*)(ws + 32768 + 3 * 65536);         // 64 KB
    int*   tok_rows   = (int*)(ws + 32768 + 4 * 65536);           // 64 KB
    size_t o = 32768 + 5 * (size_t)65536 + 32768;        // 393216
    unsigned short* xb   = (unsigned short*)(ws + o); o += (size_t)T_TOK * HID * 2;
    unsigned short* wg_t = (unsigned short*)(ws + o); o += (size_t)NE * INTER * HID * 2;
    unsigned short* wu_t = (unsigned short*)(ws + o); o += (size_t)NE * INTER * HID * 2;
    unsigned short* wd_t = (unsigned short*)(ws + o); o += (size_t)NE * HID * INTER * 2;
    unsigned short* h_buf = (unsigned short*)(ws + o); o += (size_t)NROWS * INTER * 2;
    unsigned short* y_buf = (unsigned short*)(ws + o); o += (size_t)NROWS * HID * 2;

    moe_router<<<RBLK, 256, 0, stream>>>(x, gate_w, xb, logits_out,
                                         topk_idx, topk_w, hist_g);
    moe_scan<<<1, 256, 0, stream>>>(hist_g, offsets, block_base, wl, n_wl,
                                    wl256, n_wl256);
    moe_scatter<<<RBLK, 64, 0, stream>>>(topk_idx, topk_w, block_base,
                                         row_token, row_w, tok_rows);
    moe_transpose_cast<<<dim3(INTER / 64, HID / 64, NE), 256, 0, stream>>>(w_gate, wg_t, HID, INTER);
    moe_transpose_cast<<<dim3(INTER / 64, HID / 64, NE), 256, 0, stream>>>(w_up,   wu_t, HID, INTER);
    moe_transpose_cast<<<dim3(HID / 64, INTER / 64, NE), 256, 0, stream>>>(w_down, wd_t, INTER, HID);

    moe_gemm1<<<dim3(GX1, MAXWL256), 512, 0, stream>>>(
        xb, wg_t, wu_t, offsets, row_token, wl256, n_wl256, h_buf);
    moe_gemm2<<<dim3(GX2, MAXWL), 256, 0, stream>>>(
        h_buf, wd_t, offsets, row_w, wl, n_wl, y_buf);
    moe_combine<<<(T_TOK * HID / 8) / 256, 256, 0, stream>>>(y_buf, tok_rows, out);
}

// Round 5
// 443.000 us; speedup vs baseline: 1.0457x; 1.0457x over previous
//
#include <hip/hip_runtime.h>
#include <hip/hip_bf16.h>
#include <math.h>

// Problem constants (from reference)
#define T_TOK 8192            // B*S = 4*2048
#define HID   1024
#define NE    8
#define TOPKN 2
#define INTER 1408
#define NROWS (T_TOK*TOPKN)   // 16384 routed (token,expert) rows
#define MAXWL256 72           // max 256-row worklist entries (gemm1/gemm2)
#define RBLK  256             // router blocks (32 tokens each)
#define GX1   (INTER/128)     // gemm1 grid.x = 11
#define GX2   (HID/256)       // gemm2 grid.x = 4

typedef __attribute__((ext_vector_type(8))) __bf16 bf16x8;
typedef __attribute__((ext_vector_type(4))) float f32x4;
typedef __attribute__((ext_vector_type(4))) unsigned int u32x4;

__device__ __forceinline__ unsigned short f2bf(float f) {
    unsigned int u = __builtin_bit_cast(unsigned int, f);
    unsigned int lsb = (u >> 16) & 1u;
    u += 0x7fffu + lsb;            // round-to-nearest-even
    return (unsigned short)(u >> 16);
}

// async global->LDS, 16B per lane (m97 pattern).
__device__ __forceinline__ void gl2lds16(const void* g, void* l) {
    __builtin_amdgcn_global_load_lds(
        (const __attribute__((address_space(1))) unsigned int*)g,
        (__attribute__((address_space(3))) unsigned int*)l, 16, 0, 0);
}

// ---------------------------------------------------------------- router
__global__ __launch_bounds__(256) void moe_router(
    const float* __restrict__ x, const float* __restrict__ gate_w,
    unsigned short* __restrict__ xb, float* __restrict__ logits_out,
    int* __restrict__ topk_idx, float* __restrict__ topk_w,
    int* __restrict__ hist_g)
{
    __shared__ int lh[NE];
    int tid = threadIdx.x, wave = tid >> 6, lane = tid & 63;
    if (tid < NE) lh[tid] = 0;
    __syncthreads();

#pragma unroll 1
    for (int i = 0; i < 8; i++) {
        int t = blockIdx.x * 32 + wave * 8 + i;
        const float4* xr = (const float4*)(x + (size_t)t * HID);
        float acc[NE];
#pragma unroll
        for (int e = 0; e < NE; e++) acc[e] = 0.f;
#pragma unroll
        for (int j = 0; j < 4; j++) {
            float4 xv = xr[j * 64 + lane];
            ushort4 pk;
            pk.x = f2bf(xv.x); pk.y = f2bf(xv.y);
            pk.z = f2bf(xv.z); pk.w = f2bf(xv.w);
            *(ushort4*)(xb + (size_t)t * HID + j * 256 + lane * 4) = pk;
#pragma unroll
            for (int e = 0; e < NE; e++) {
                float4 gv = *(const float4*)(gate_w + e * HID + j * 256 + lane * 4);
                acc[e] += xv.x * gv.x + xv.y * gv.y + xv.z * gv.z + xv.w * gv.w;
            }
        }
#pragma unroll
        for (int e = 0; e < NE; e++) {
            float v = acc[e];
#pragma unroll
            for (int off = 32; off; off >>= 1) v += __shfl_xor(v, off, 64);
            acc[e] = v;
        }
        if (lane == 0) {
            float m = acc[0];
#pragma unroll
            for (int e = 1; e < NE; e++) m = fmaxf(m, acc[e]);
            float p[NE]; float s = 0.f;
#pragma unroll
            for (int e = 0; e < NE; e++) { p[e] = expf(acc[e] - m); s += p[e]; }
            float inv = 1.f / s;
#pragma unroll
            for (int e = 0; e < NE; e++) logits_out[(size_t)t * NE + e] = acc[e];
            int i0 = 0;
#pragma unroll
            for (int e = 1; e < NE; e++) if (p[e] > p[i0]) i0 = e;
            int i1 = (i0 == 0) ? 1 : 0;
#pragma unroll
            for (int e = 0; e < NE; e++) if (e != i0 && p[e] > p[i1]) i1 = e;
            topk_idx[2 * t]     = i0; topk_w[2 * t]     = p[i0] * inv;
            topk_idx[2 * t + 1] = i1; topk_w[2 * t + 1] = p[i1] * inv;
            atomicAdd(&lh[i0], 1);
            atomicAdd(&lh[i1], 1);
        }
    }
    __syncthreads();
    if (tid < NE) hist_g[blockIdx.x * NE + tid] = lh[tid];
}

// ---------------------------------------------------------------- scan
__global__ __launch_bounds__(256) void moe_scan(
    const int* __restrict__ hist_g, int* __restrict__ offsets,
    int* __restrict__ block_base, int* __restrict__ wl256, int* __restrict__ n_wl256)
{
    __shared__ int h[RBLK * NE];
    __shared__ int cnt[NE], offs[NE];
    int tid = threadIdx.x;
    for (int i = tid; i < RBLK * NE; i += 256) h[i] = hist_g[i];
    __syncthreads();
    {
        int e = tid >> 5, g = tid & 31;
        int s = 0;
        for (int b = g; b < RBLK; b += 32) s += h[b * NE + e];
#pragma unroll
        for (int off2 = 16; off2; off2 >>= 1) s += __shfl_xor(s, off2, 32);
        if (g == 0) cnt[e] = s;
    }
    __syncthreads();
    if (tid == 0) {
        int s = 0;
        for (int e = 0; e < NE; e++) { offs[e] = s; offsets[e] = s; s += cnt[e]; }
        offsets[NE] = s;
        int n2 = 0;
        for (int e = 0; e < NE; e++)
            for (int r0 = 0; r0 < cnt[e]; r0 += 256)
                wl256[n2++] = (e << 24) | r0;
        *n_wl256 = n2;
    }
    __syncthreads();
    if (tid < NE) {
        int run = offs[tid];
        for (int b = 0; b < RBLK; b++) {
            block_base[b * NE + tid] = run;
            run += h[b * NE + tid];
        }
    }
}

// ---------------------------------------------------------------- scatter
__global__ __launch_bounds__(64) void moe_scatter(
    const int* __restrict__ topk_idx, const float* __restrict__ topk_w,
    const int* __restrict__ block_base, int* __restrict__ row_token,
    float* __restrict__ row_w, int* __restrict__ tok_rows)
{
    __shared__ int base[NE];
    int tid = threadIdx.x;
    if (tid < NE) base[tid] = block_base[blockIdx.x * NE + tid];
    __syncthreads();
    int idx = blockIdx.x * 64 + tid;     // = 2*t + k
    int e = topk_idx[idx];
    int pos = atomicAdd(&base[e], 1);    // LDS atomic
    row_token[pos] = idx >> 1;
    row_w[pos] = topk_w[idx];
    tok_rows[idx] = pos;
}

// ---------------------------------------------------------------- transpose+cast (all 3 weights, fused)
// z = blockIdx.y: matrix m = z>>3 (0=w_gate,1=w_up,2=w_down), expert e = z&7.
__global__ __launch_bounds__(256) void moe_transpose_all(
    const float* __restrict__ w_gate, const float* __restrict__ w_up,
    const float* __restrict__ w_down,
    unsigned short* __restrict__ wg_t, unsigned short* __restrict__ wu_t,
    unsigned short* __restrict__ wd_t)
{
    __shared__ float tile[64][65];
    int z = blockIdx.y;
    int m = z >> 3, e = z & 7;
    const float* in; unsigned short* out; int R_, C_;
    if (m == 0)      { in = w_gate; out = wg_t; R_ = HID;   C_ = INTER; }
    else if (m == 1) { in = w_up;   out = wu_t; R_ = HID;   C_ = INTER; }
    else             { in = w_down; out = wd_t; R_ = INTER; C_ = HID;   }
    int ntx = C_ >> 6;
    int bx = (int)blockIdx.x % ntx, by = (int)blockIdx.x / ntx;
    const float* ine = in + (size_t)e * R_ * C_;
    unsigned short* oute = out + (size_t)e * R_ * C_;
    int c0 = bx * 64, r0 = by * 64;
    int tid = threadIdx.x;
    int lr = tid >> 4;          // 0..15
    int lc = tid & 15;          // float4 column chunk
#pragma unroll
    for (int j = 0; j < 4; j++) {
        int r = lr + j * 16;
        float4 v = *(const float4*)(ine + (size_t)(r0 + r) * C_ + c0 + lc * 4);
        tile[r][lc * 4 + 0] = v.x; tile[r][lc * 4 + 1] = v.y;
        tile[r][lc * 4 + 2] = v.z; tile[r][lc * 4 + 3] = v.w;
    }
    __syncthreads();
#pragma unroll
    for (int j = 0; j < 4; j++) {
        int c = (tid >> 4) + j * 16;
        int r = (tid & 15) * 4;
        ushort4 pk;
        pk.x = f2bf(tile[r + 0][c]);
        pk.y = f2bf(tile[r + 1][c]);
        pk.z = f2bf(tile[r + 2][c]);
        pk.w = f2bf(tile[r + 3][c]);
        *(ushort4*)(oute + (size_t)(c0 + c) * R_ + r0 + r) = pk;
    }
}

// ---------------------------------------------------------------- grouped GEMM1
// 256x256 tile, 512 threads (8 waves, 2M x 4N; per-wave 128x64). K-tile 64 in
// two 32-K slices; 4 phases per K-tile. PER-PHASE derived gates (R4 fix):
//   phase 1 reads A(kt)s0 + B(kt)s0: 8 outstanding, need oldest 4 -> vmcnt(4)
//   phase 2 reads B(kt)s0 (3rd-oldest already forced done)      -> vmcnt(6)
//   phase 3 reads A(kt)s1 + B(kt)s1                             -> vmcnt(4)
//   phase 4 reads B(kt)s1                                       -> vmcnt(6)
// (R3/R4's all-vmcnt(6) left B(kt)s0/s1 un-drained at phases 1/3 -> race.)
__global__ __launch_bounds__(512, 2) void moe_gemm1(
    const unsigned short* __restrict__ xb,
    const unsigned short* __restrict__ wg_t,   // [NE][INTER][HID]
    const unsigned short* __restrict__ wu_t,   // [NE][INTER][HID]
    const int* __restrict__ offsets, const int* __restrict__ row_token,
    const int* __restrict__ wl, const int* __restrict__ n_wl,
    unsigned short* __restrict__ h_buf)        // [NROWS][INTER]
{
    if ((int)blockIdx.y >= *n_wl) return;
    int wle = wl[blockIdx.y];
    int e = wle >> 24, row0 = wle & 0xffffff;
    int off = offsets[e], cnt = offsets[e + 1] - off;
    int i0 = blockIdx.x * 128;

    __shared__ __align__(16) unsigned short As[32768];  // 64 KB: [2][2][256][32]
    __shared__ __align__(16) unsigned short Bs[32768];  // 64 KB

    int tid = threadIdx.x, wave = tid >> 6, lane = tid & 63;
    int wm = wave & 1, wn = wave >> 1;
    int l16 = lane & 15, quad = lane >> 4;
    int fsw = (l16 >> 1) & 3;                  // frag-read chunk xor

    int kswz = ((lane & 3) ^ ((lane >> 3) & 3)) * 8;
    int r0s = wave * 32 + (lane >> 2);         // staging row, load j=0
    int r1s = r0s + 16;                        // load j=1

    int gA0 = row0 + r0s, gA1 = row0 + r1s;
    int tok0 = row_token[off + ((gA0 < cnt) ? gA0 : 0)];
    int tok1 = row_token[off + ((gA1 < cnt) ? gA1 : 0)];
    const unsigned short* aptr0 = xb + (size_t)tok0 * HID + kswz;
    const unsigned short* aptr1 = xb + (size_t)tok1 * HID + kswz;

    int ic0 = i0 + (r0s >> 6) * 32 + (r0s & 31);
    int ic1 = i0 + (r1s >> 6) * 32 + (r1s & 31);
    const unsigned short* bptr0 =
        (((r0s >> 5) & 1) ? wu_t : wg_t) + (size_t)e * INTER * HID + (size_t)ic0 * HID + kswz;
    const unsigned short* bptr1 =
        (((r1s >> 5) & 1) ? wu_t : wg_t) + (size_t)e * INTER * HID + (size_t)ic1 * HID + kswz;

    f32x4 acc[8][4];
#pragma unroll
    for (int mi = 0; mi < 8; mi++)
#pragma unroll
        for (int ni = 0; ni < 4; ni++) acc[mi][ni] = {0.f, 0.f, 0.f, 0.f};

    // prologue: stage all 4 halves of K-tile 0 into buf 0, full drain once.
    {
        unsigned short* dA = &As[wave * 1024];
        unsigned short* dB = &Bs[wave * 1024];
        gl2lds16(aptr0, dA);            gl2lds16(aptr1, dA + 512);
        gl2lds16(bptr0, dB);            gl2lds16(bptr1, dB + 512);
        gl2lds16(aptr0 + 32, dA + 8192); gl2lds16(aptr1 + 32, dA + 8192 + 512);
        gl2lds16(bptr0 + 32, dB + 8192); gl2lds16(bptr1 + 32, dB + 8192 + 512);
    }
    __syncthreads();

#pragma unroll 1
    for (int kt = 0; kt < 16; kt++) {
        const unsigned short* Ac = &As[(kt & 1) << 14];
        const unsigned short* Bc = &Bs[(kt & 1) << 14];
        unsigned short* An = &As[(((kt + 1) & 1) << 14) + wave * 1024];
        unsigned short* Bn = &Bs[(((kt + 1) & 1) << 14) + wave * 1024];
        int kb = (kt + 1) * 64;
        bool more = kt < 15;
        bf16x8 a[8], b0, b1;

        // ---------- phase 1: slice 0, ni 0-1; stage A-ks0(kt+1)
        asm volatile("s_waitcnt vmcnt(4)" ::: "memory");
        __builtin_amdgcn_s_barrier();
#pragma unroll
        for (int mi = 0; mi < 8; mi++)
            a[mi] = *(const bf16x8*)&Ac[(wm * 128 + mi * 16 + l16) * 32 + (quad ^ fsw) * 8];
        b0 = *(const bf16x8*)&Bc[(wn * 64 + l16) * 32 + (quad ^ fsw) * 8];
        b1 = *(const bf16x8*)&Bc[(wn * 64 + 16 + l16) * 32 + (quad ^ fsw) * 8];
        if (more) { gl2lds16(aptr0 + kb, An); gl2lds16(aptr1 + kb, An + 512); }
        __builtin_amdgcn_s_setprio(1);
#pragma unroll
        for (int mi = 0; mi < 8; mi++) {
            acc[mi][0] = __builtin_amdgcn_mfma_f32_16x16x32_bf16(a[mi], b0, acc[mi][0], 0, 0, 0);
            acc[mi][1] = __builtin_amdgcn_mfma_f32_16x16x32_bf16(a[mi], b1, acc[mi][1], 0, 0, 0);
        }
        __builtin_amdgcn_s_setprio(0);

        // ---------- phase 2: slice 0, ni 2-3; stage B-ks0(kt+1)
        asm volatile("s_waitcnt vmcnt(6)" ::: "memory");
        __builtin_amdgcn_s_barrier();
        b0 = *(const bf16x8*)&Bc[(wn * 64 + 32 + l16) * 32 + (quad ^ fsw) * 8];
        b1 = *(const bf16x8*)&Bc[(wn * 64 + 48 + l16) * 32 + (quad ^ fsw) * 8];
        if (more) { gl2lds16(bptr0 + kb, Bn); gl2lds16(bptr1 + kb, Bn + 512); }
        __builtin_amdgcn_s_setprio(1);
#pragma unroll
        for (int mi = 0; mi < 8; mi++) {
            acc[mi][2] = __builtin_amdgcn_mfma_f32_16x16x32_bf16(a[mi], b0, acc[mi][2], 0, 0, 0);
            acc[mi][3] = __builtin_amdgcn_mfma_f32_16x16x32_bf16(a[mi], b1, acc[mi][3], 0, 0, 0);
        }
        __builtin_amdgcn_s_setprio(0);

        // ---------- phase 3: slice 1, ni 0-1; stage A-ks1(kt+1)
        asm volatile("s_waitcnt vmcnt(4)" ::: "memory");
        __builtin_amdgcn_s_barrier();
#pragma unroll
        for (int mi = 0; mi < 8; mi++)
            a[mi] = *(const bf16x8*)&Ac[8192 + (wm * 128 + mi * 16 + l16) * 32 + (quad ^ fsw) * 8];
        b0 = *(const bf16x8*)&Bc[8192 + (wn * 64 + l16) * 32 + (quad ^ fsw) * 8];
        b1 = *(const bf16x8*)&Bc[8192 + (wn * 64 + 16 + l16) * 32 + (quad ^ fsw) * 8];
        if (more) { gl2lds16(aptr0 + kb + 32, An + 8192); gl2lds16(aptr1 + kb + 32, An + 8192 + 512); }
        __builtin_amdgcn_s_setprio(1);
#pragma unroll
        for (int mi = 0; mi < 8; mi++) {
            acc[mi][0] = __builtin_amdgcn_mfma_f32_16x16x32_bf16(a[mi], b0, acc[mi][0], 0, 0, 0);
            acc[mi][1] = __builtin_amdgcn_mfma_f32_16x16x32_bf16(a[mi], b1, acc[mi][1], 0, 0, 0);
        }
        __builtin_amdgcn_s_setprio(0);

        // ---------- phase 4: slice 1, ni 2-3; stage B-ks1(kt+1)
        asm volatile("s_waitcnt vmcnt(6)" ::: "memory");
        __builtin_amdgcn_s_barrier();
        b0 = *(const bf16x8*)&Bc[8192 + (wn * 64 + 32 + l16) * 32 + (quad ^ fsw) * 8];
        b1 = *(const bf16x8*)&Bc[8192 + (wn * 64 + 48 + l16) * 32 + (quad ^ fsw) * 8];
        if (more) { gl2lds16(bptr0 + kb + 32, Bn + 8192); gl2lds16(bptr1 + kb + 32, Bn + 8192 + 512); }
        __builtin_amdgcn_s_setprio(1);
#pragma unroll
        for (int mi = 0; mi < 8; mi++) {
            acc[mi][2] = __builtin_amdgcn_mfma_f32_16x16x32_bf16(a[mi], b0, acc[mi][2], 0, 0, 0);
            acc[mi][3] = __builtin_amdgcn_mfma_f32_16x16x32_bf16(a[mi], b1, acc[mi][3], 0, 0, 0);
        }
        __builtin_amdgcn_s_setprio(0);
    }

    // epilogue: silu(g)*u -> bf16  (C/D: col=lane&15, row=quad*4+reg)
#pragma unroll
    for (int mi = 0; mi < 8; mi++)
#pragma unroll
        for (int np = 0; np < 2; np++)
#pragma unroll
            for (int r = 0; r < 4; r++) {
                int ml = wm * 128 + mi * 16 + quad * 4 + r;
                int row = row0 + ml;
                if (row < cnt) {
                    float g = acc[mi][np][r], u = acc[mi][np + 2][r];
                    float hv = (g / (1.f + expf(-g))) * u;
                    h_buf[(size_t)(off + row) * INTER + i0 + wn * 32 + np * 16 + l16] = f2bf(hv);
                }
            }
}

// ---------------------------------------------------------------- grouped GEMM2
// Same 4-phase 256x256 structure as gemm1, same per-phase derived gates.
// B = wd_t rows h0..h0+255 (identity col map), K=INTER (22 K-tiles).
__global__ __launch_bounds__(512, 2) void moe_gemm2(
    const unsigned short* __restrict__ h_buf,  // [NROWS][INTER]
    const unsigned short* __restrict__ wd_t,   // [NE][HID][INTER]
    const int* __restrict__ offsets, const float* __restrict__ row_w,
    const int* __restrict__ wl, const int* __restrict__ n_wl,
    unsigned short* __restrict__ y_buf)        // [NROWS][HID]
{
    if ((int)blockIdx.y >= *n_wl) return;
    int wle = wl[blockIdx.y];
    int e = wle >> 24, row0 = wle & 0xffffff;
    int off = offsets[e], cnt = offsets[e + 1] - off;
    int h0 = blockIdx.x * 256;

    __shared__ __align__(16) unsigned short As[32768];  // 64 KB: [2][2][256][32]
    __shared__ __align__(16) unsigned short Bs[32768];  // 64 KB

    int tid = threadIdx.x, wave = tid >> 6, lane = tid & 63;
    int wm = wave & 1, wn = wave >> 1;
    int l16 = lane & 15, quad = lane >> 4;
    int fsw = (l16 >> 1) & 3;

    int kswz = ((lane & 3) ^ ((lane >> 3) & 3)) * 8;
    int r0s = wave * 32 + (lane >> 2);
    int r1s = r0s + 16;

    int gA0 = row0 + r0s, gA1 = row0 + r1s;
    const unsigned short* aptr0 = h_buf + (size_t)(off + ((gA0 < cnt) ? gA0 : 0)) * INTER + kswz;
    const unsigned short* aptr1 = h_buf + (size_t)(off + ((gA1 < cnt) ? gA1 : 0)) * INTER + kswz;

    const unsigned short* bptr0 = wd_t + (size_t)e * HID * INTER + (size_t)(h0 + r0s) * INTER + kswz;
    const unsigned short* bptr1 = wd_t + (size_t)e * HID * INTER + (size_t)(h0 + r1s) * INTER + kswz;

    f32x4 acc[8][4];
#pragma unroll
    for (int mi = 0; mi < 8; mi++)
#pragma unroll
        for (int ni = 0; ni < 4; ni++) acc[mi][ni] = {0.f, 0.f, 0.f, 0.f};

    // prologue: stage all 4 halves of K-tile 0 into buf 0, full drain once.
    {
        unsigned short* dA = &As[wave * 1024];
        unsigned short* dB = &Bs[wave * 1024];
        gl2lds16(aptr0, dA);            gl2lds16(aptr1, dA + 512);
        gl2lds16(bptr0, dB);            gl2lds16(bptr1, dB + 512);
        gl2lds16(aptr0 + 32, dA + 8192); gl2lds16(aptr1 + 32, dA + 8192 + 512);
        gl2lds16(bptr0 + 32, dB + 8192); gl2lds16(bptr1 + 32, dB + 8192 + 512);
    }
    __syncthreads();

#pragma unroll 1
    for (int kt = 0; kt < 22; kt++) {
        const unsigned short* Ac = &As[(kt & 1) << 14];
        const unsigned short* Bc = &Bs[(kt & 1) << 14];
        unsigned short* An = &As[(((kt + 1) & 1) << 14) + wave * 1024];
        unsigned short* Bn = &Bs[(((kt + 1) & 1) << 14) + wave * 1024];
        int kb = (kt + 1) * 64;
        bool more = kt < 21;
        bf16x8 a[8], b0, b1;

        // ---------- phase 1: slice 0, ni 0-1; stage A-ks0(kt+1)
        asm volatile("s_waitcnt vmcnt(4)" ::: "memory");
        __builtin_amdgcn_s_barrier();
#pragma unroll
        for (int mi = 0; mi < 8; mi++)
            a[mi] = *(const bf16x8*)&Ac[(wm * 128 + mi * 16 + l16) * 32 + (quad ^ fsw) * 8];
        b0 = *(const bf16x8*)&Bc[(wn * 64 + l16) * 32 + (quad ^ fsw) * 8];
        b1 = *(const bf16x8*)&Bc[(wn * 64 + 16 + l16) * 32 + (quad ^ fsw) * 8];
        if (more) { gl2lds16(aptr0 + kb, An); gl2lds16(aptr1 + kb, An + 512); }
        __builtin_amdgcn_s_setprio(1);
#pragma unroll
        for (int mi = 0; mi < 8; mi++) {
            acc[mi][0] = __builtin_amdgcn_mfma_f32_16x16x32_bf16(a[mi], b0, acc[mi][0], 0, 0, 0);
            acc[mi][1] = __builtin_amdgcn_mfma_f32_16x16x32_bf16(a[mi], b1, acc[mi][1], 0, 0, 0);
        }
        __builtin_amdgcn_s_setprio(0);

        // ---------- phase 2: slice 0, ni 2-3; stage B-ks0(kt+1)
        asm volatile("s_waitcnt vmcnt(6)" ::: "memory");
        __builtin_amdgcn_s_barrier();
        b0 = *(const bf16x8*)&Bc[(wn * 64 + 32 + l16) * 32 + (quad ^ fsw) * 8];
        b1 = *(const bf16x8*)&Bc[(wn * 64 + 48 + l16) * 32 + (quad ^ fsw) * 8];
        if (more) { gl2lds16(bptr0 + kb, Bn); gl2lds16(bptr1 + kb, Bn + 512); }
        __builtin_amdgcn_s_setprio(1);
#pragma unroll
        for (int mi = 0; mi < 8; mi++) {
            acc[mi][2] = __builtin_amdgcn_mfma_f32_16x16x32_bf16(a[mi], b0, acc[mi][2], 0, 0, 0);
            acc[mi][3] = __builtin_amdgcn_mfma_f32_16x16x32_bf16(a[mi], b1, acc[mi][3], 0, 0, 0);
        }
        __builtin_amdgcn_s_setprio(0);

        // ---------- phase 3: slice 1, ni 0-1; stage A-ks1(kt+1)
        asm volatile("s_waitcnt vmcnt(4)" ::: "memory");
        __builtin_amdgcn_s_barrier();
#pragma unroll
        for (int mi = 0; mi < 8; mi++)
            a[mi] = *(const bf16x8*)&Ac[8192 + (wm * 128 + mi * 16 + l16) * 32 + (quad ^ fsw) * 8];
        b0 = *(const bf16x8*)&Bc[8192 + (wn * 64 + l16) * 32 + (quad ^ fsw) * 8];
        b1 = *(const bf16x8*)&Bc[8192 + (wn * 64 + 16 + l16) * 32 + (quad ^ fsw) * 8];
        if (more) { gl2lds16(aptr0 + kb + 32, An + 8192); gl2lds16(aptr1 + kb + 32, An + 8192 + 512); }
        __builtin_amdgcn_s_setprio(1);
#pragma unroll
        for (int mi = 0; mi < 8; mi++) {
            acc[mi][0] = __builtin_amdgcn_mfma_f32_16x16x32_bf16(a[mi], b0, acc[mi][0], 0, 0, 0);
            acc[mi][1] = __builtin_amdgcn_mfma_f32_16x16x32_bf16(a[mi], b1, acc[mi][1], 0, 0, 0);
        }
        __builtin_amdgcn_s_setprio(0);

        // ---------- phase 4: slice 1, ni 2-3; stage B-ks1(kt+1)
        asm volatile("s_waitcnt vmcnt(6)" ::: "memory");
        __builtin_amdgcn_s_barrier();
        b0 = *(const bf16x8*)&Bc[8192 + (wn * 64 + 32 + l16) * 32 + (quad ^ fsw) * 8];
        b1 = *(const bf16x8*)&Bc[8192 + (wn * 64 + 48 + l16) * 32 + (quad ^ fsw) * 8];
        if (more) { gl2lds16(bptr0 + kb + 32, Bn + 8192); gl2lds16(bptr1 + kb + 32, Bn + 8192 + 512); }
        __builtin_amdgcn_s_setprio(1);
#pragma unroll
        for (int mi = 0; mi < 8; mi++) {
            acc[mi][2] = __builtin_amdgcn_mfma_f32_16x16x32_bf16(a[mi], b0, acc[mi][2], 0, 0, 0);
            acc[mi][3] = __builtin_amdgcn_mfma_f32_16x16x32_bf16(a[mi], b1, acc[mi][3], 0, 0, 0);
        }
        __builtin_amdgcn_s_setprio(0);
    }

    // epilogue: scale by row_w -> bf16  (C/D: col=lane&15, row=quad*4+reg)
#pragma unroll
    for (int mi = 0; mi < 8; mi++)
#pragma unroll
        for (int ni = 0; ni < 4; ni++)
#pragma unroll
            for (int r = 0; r < 4; r++) {
                int ml = wm * 128 + mi * 16 + quad * 4 + r;
                int row = row0 + ml;
                if (row < cnt) {
                    float w = row_w[off + row];
                    y_buf[(size_t)(off + row) * HID + h0 + wn * 64 + ni * 16 + l16] =
                        f2bf(acc[mi][ni][r] * w);
                }
            }
}

// ---------------------------------------------------------------- combine
__global__ __launch_bounds__(256) void moe_combine(
    const unsigned short* __restrict__ y_buf, const int* __restrict__ tok_rows,
    float* __restrict__ out)
{
    int gid = blockIdx.x * 256 + threadIdx.x;   // T*H/8 threads
    int t = gid >> 7;
    int c = gid & 127;
    u32x4 a = *(const u32x4*)(y_buf + (size_t)tok_rows[2 * t]     * HID + c * 8);
    u32x4 b = *(const u32x4*)(y_buf + (size_t)tok_rows[2 * t + 1] * HID + c * 8);
    float res[8];
#pragma unroll
    for (int j = 0; j < 4; j++) {
        unsigned int wa = a[j], wb = b[j];
        res[2 * j]     = __builtin_bit_cast(float, wa << 16)
                       + __builtin_bit_cast(float, wb << 16);
        res[2 * j + 1] = __builtin_bit_cast(float, wa & 0xffff0000u)
                       + __builtin_bit_cast(float, wb & 0xffff0000u);
    }
    float* o = out + (size_t)t * HID + c * 8;
    *(float4*)(o)     = make_float4(res[0], res[1], res[2], res[3]);
    *(float4*)(o + 4) = make_float4(res[4], res[5], res[6], res[7]);
}

// ---------------------------------------------------------------- launch
extern "C" void kernel_launch(void* const* d_in, const int* in_sizes, int n_in,
                              void* d_out, int out_size, void* d_ws, size_t ws_size,
                              hipStream_t stream)
{
    const float* x      = (const float*)d_in[0];
    const float* gate_w = (const float*)d_in[1];
    const float* w_gate = (const float*)d_in[2];
    const float* w_up   = (const float*)d_in[3];
    const float* w_down = (const float*)d_in[4];
    float* out = (float*)d_out;                    // final [T,H] ++ logits [T,E]
    float* logits_out = out + (size_t)T_TOK * HID;

    char* ws = (char*)d_ws;
    int*   offsets    = (int*)(ws + 0);                  // 9 ints
    int*   n_wl256    = (int*)(ws + 68);
    int*   wl256      = (int*)(ws + 704);                // MAXWL256 ints (288 B)
    int*   hist_g     = (int*)(ws + 1024);               // RBLK*NE = 8 KB
    int*   block_base = (int*)(ws + 1024 + 8192);        // 8 KB
    int*   topk_idx   = (int*)(ws + 32768);                       // 64 KB
    float* topk_w     = (float*)(ws + 32768 + 65536);             // 64 KB
    int*   row_token  = (int*)(ws + 32768 + 2 * 65536);           // 64 KB
    float* row_w      = (float*)(ws + 32768 + 3 * 65536);         // 64 KB
    int*   tok_rows   = (int*)(ws + 32768 + 4 * 65536);           // 64 KB
    size_t o = 32768 + 5 * (size_t)65536 + 32768;        // 393216
    unsigned short* xb   = (unsigned short*)(ws + o); o += (size_t)T_TOK * HID * 2;
    unsigned short* wg_t = (unsigned short*)(ws + o); o += (size_t)NE * INTER * HID * 2;
    unsigned short* wu_t = (unsigned short*)(ws + o); o += (size_t)NE * INTER * HID * 2;
    unsigned short* wd_t = (unsigned short*)(ws + o); o += (size_t)NE * HID * INTER * 2;
    unsigned short* h_buf = (unsigned short*)(ws + o); o += (size_t)NROWS * INTER * 2;
    unsigned short* y_buf = (unsigned short*)(ws + o); o += (size_t)NROWS * HID * 2;

    moe_router<<<RBLK, 256, 0, stream>>>(x, gate_w, xb, logits_out,
                                         topk_idx, topk_w, hist_g);
    moe_scan<<<1, 256, 0, stream>>>(hist_g, offsets, block_base, wl256, n_wl256);
    moe_scatter<<<RBLK, 64, 0, stream>>>(topk_idx, topk_w, block_base,
                                         row_token, row_w, tok_rows);
    moe_transpose_all<<<dim3(352, 24), 256, 0, stream>>>(
        w_gate, w_up, w_down, wg_t, wu_t, wd_t);

    moe_gemm1<<<dim3(GX1, MAXWL256), 512, 0, stream>>>(
        xb, wg_t, wu_t, offsets, row_token, wl256, n_wl256, h_buf);
    moe_gemm2<<<dim3(GX2, MAXWL256), 512, 0, stream>>>(
        h_buf, wd_t, offsets, row_w, wl256, n_wl256, y_buf);
    moe_combine<<<(T_TOK * HID / 8) / 256, 256, 0, stream>>>(y_buf, tok_rows, out);
}

// Round 6
// 439.374 us; speedup vs baseline: 1.0543x; 1.0083x over previous
//
#include <hip/hip_runtime.h>
#include <hip/hip_bf16.h>
#include <math.h>

// Problem constants (from reference)
#define T_TOK 8192            // B*S = 4*2048
#define HID   1024
#define NE    8
#define TOPKN 2
#define INTER 1408
#define NROWS (T_TOK*TOPKN)   // 16384 routed (token,expert) rows
#define MAXWL256 72           // max 256-row worklist entries (gemm1/gemm2)
#define RBLK  256             // router blocks (32 tokens each)
#define GX1   (INTER/128)     // gemm1 grid.x = 11
#define GX2   (HID/128)       // gemm2 grid.x = 8 (128-col tiles: 544 real blocks
                              //   = 2.1/CU vs 256-col's 1.06/CU makespan disaster)

typedef __attribute__((ext_vector_type(8))) __bf16 bf16x8;
typedef __attribute__((ext_vector_type(4))) float f32x4;
typedef __attribute__((ext_vector_type(4))) unsigned int u32x4;

__device__ __forceinline__ unsigned short f2bf(float f) {
    unsigned int u = __builtin_bit_cast(unsigned int, f);
    unsigned int lsb = (u >> 16) & 1u;
    u += 0x7fffu + lsb;            // round-to-nearest-even
    return (unsigned short)(u >> 16);
}

// async global->LDS, 16B per lane (m97 pattern).
__device__ __forceinline__ void gl2lds16(const void* g, void* l) {
    __builtin_amdgcn_global_load_lds(
        (const __attribute__((address_space(1))) unsigned int*)g,
        (__attribute__((address_space(3))) unsigned int*)l, 16, 0, 0);
}

// ---------------------------------------------------------------- router
__global__ __launch_bounds__(256) void moe_router(
    const float* __restrict__ x, const float* __restrict__ gate_w,
    unsigned short* __restrict__ xb, float* __restrict__ logits_out,
    int* __restrict__ topk_idx, float* __restrict__ topk_w,
    int* __restrict__ hist_g)
{
    __shared__ int lh[NE];
    int tid = threadIdx.x, wave = tid >> 6, lane = tid & 63;
    if (tid < NE) lh[tid] = 0;
    __syncthreads();

#pragma unroll 1
    for (int i = 0; i < 8; i++) {
        int t = blockIdx.x * 32 + wave * 8 + i;
        const float4* xr = (const float4*)(x + (size_t)t * HID);
        float acc[NE];
#pragma unroll
        for (int e = 0; e < NE; e++) acc[e] = 0.f;
#pragma unroll
        for (int j = 0; j < 4; j++) {
            float4 xv = xr[j * 64 + lane];
            ushort4 pk;
            pk.x = f2bf(xv.x); pk.y = f2bf(xv.y);
            pk.z = f2bf(xv.z); pk.w = f2bf(xv.w);
            *(ushort4*)(xb + (size_t)t * HID + j * 256 + lane * 4) = pk;
#pragma unroll
            for (int e = 0; e < NE; e++) {
                float4 gv = *(const float4*)(gate_w + e * HID + j * 256 + lane * 4);
                acc[e] += xv.x * gv.x + xv.y * gv.y + xv.z * gv.z + xv.w * gv.w;
            }
        }
#pragma unroll
        for (int e = 0; e < NE; e++) {
            float v = acc[e];
#pragma unroll
            for (int off = 32; off; off >>= 1) v += __shfl_xor(v, off, 64);
            acc[e] = v;
        }
        if (lane == 0) {
            float m = acc[0];
#pragma unroll
            for (int e = 1; e < NE; e++) m = fmaxf(m, acc[e]);
            float p[NE]; float s = 0.f;
#pragma unroll
            for (int e = 0; e < NE; e++) { p[e] = expf(acc[e] - m); s += p[e]; }
            float inv = 1.f / s;
#pragma unroll
            for (int e = 0; e < NE; e++) logits_out[(size_t)t * NE + e] = acc[e];
            int i0 = 0;
#pragma unroll
            for (int e = 1; e < NE; e++) if (p[e] > p[i0]) i0 = e;
            int i1 = (i0 == 0) ? 1 : 0;
#pragma unroll
            for (int e = 0; e < NE; e++) if (e != i0 && p[e] > p[i1]) i1 = e;
            topk_idx[2 * t]     = i0; topk_w[2 * t]     = p[i0] * inv;
            topk_idx[2 * t + 1] = i1; topk_w[2 * t + 1] = p[i1] * inv;
            atomicAdd(&lh[i0], 1);
            atomicAdd(&lh[i1], 1);
        }
    }
    __syncthreads();
    if (tid < NE) hist_g[blockIdx.x * NE + tid] = lh[tid];
}

// ---------------------------------------------------------------- scan
__global__ __launch_bounds__(256) void moe_scan(
    const int* __restrict__ hist_g, int* __restrict__ offsets,
    int* __restrict__ block_base, int* __restrict__ wl256, int* __restrict__ n_wl256)
{
    __shared__ int h[RBLK * NE];
    __shared__ int cnt[NE], offs[NE];
    int tid = threadIdx.x;
    for (int i = tid; i < RBLK * NE; i += 256) h[i] = hist_g[i];
    __syncthreads();
    {
        int e = tid >> 5, g = tid & 31;
        int s = 0;
        for (int b = g; b < RBLK; b += 32) s += h[b * NE + e];
#pragma unroll
        for (int off2 = 16; off2; off2 >>= 1) s += __shfl_xor(s, off2, 32);
        if (g == 0) cnt[e] = s;
    }
    __syncthreads();
    if (tid == 0) {
        int s = 0;
        for (int e = 0; e < NE; e++) { offs[e] = s; offsets[e] = s; s += cnt[e]; }
        offsets[NE] = s;
        int n2 = 0;
        for (int e = 0; e < NE; e++)
            for (int r0 = 0; r0 < cnt[e]; r0 += 256)
                wl256[n2++] = (e << 24) | r0;
        *n_wl256 = n2;
    }
    __syncthreads();
    if (tid < NE) {
        int run = offs[tid];
        for (int b = 0; b < RBLK; b++) {
            block_base[b * NE + tid] = run;
            run += h[b * NE + tid];
        }
    }
}

// ---------------------------------------------------------------- scatter
__global__ __launch_bounds__(64) void moe_scatter(
    const int* __restrict__ topk_idx, const float* __restrict__ topk_w,
    const int* __restrict__ block_base, int* __restrict__ row_token,
    float* __restrict__ row_w, int* __restrict__ tok_rows)
{
    __shared__ int base[NE];
    int tid = threadIdx.x;
    if (tid < NE) base[tid] = block_base[blockIdx.x * NE + tid];
    __syncthreads();
    int idx = blockIdx.x * 64 + tid;     // = 2*t + k
    int e = topk_idx[idx];
    int pos = atomicAdd(&base[e], 1);    // LDS atomic
    row_token[pos] = idx >> 1;
    row_w[pos] = topk_w[idx];
    tok_rows[idx] = pos;
}

// ---------------------------------------------------------------- transpose+cast (all 3 weights, fused)
__global__ __launch_bounds__(256) void moe_transpose_all(
    const float* __restrict__ w_gate, const float* __restrict__ w_up,
    const float* __restrict__ w_down,
    unsigned short* __restrict__ wg_t, unsigned short* __restrict__ wu_t,
    unsigned short* __restrict__ wd_t)
{
    __shared__ float tile[64][65];
    int z = blockIdx.y;
    int m = z >> 3, e = z & 7;
    const float* in; unsigned short* out; int R_, C_;
    if (m == 0)      { in = w_gate; out = wg_t; R_ = HID;   C_ = INTER; }
    else if (m == 1) { in = w_up;   out = wu_t; R_ = HID;   C_ = INTER; }
    else             { in = w_down; out = wd_t; R_ = INTER; C_ = HID;   }
    int ntx = C_ >> 6;
    int bx = (int)blockIdx.x % ntx, by = (int)blockIdx.x / ntx;
    const float* ine = in + (size_t)e * R_ * C_;
    unsigned short* oute = out + (size_t)e * R_ * C_;
    int c0 = bx * 64, r0 = by * 64;
    int tid = threadIdx.x;
    int lr = tid >> 4;          // 0..15
    int lc = tid & 15;          // float4 column chunk
#pragma unroll
    for (int j = 0; j < 4; j++) {
        int r = lr + j * 16;
        float4 v = *(const float4*)(ine + (size_t)(r0 + r) * C_ + c0 + lc * 4);
        tile[r][lc * 4 + 0] = v.x; tile[r][lc * 4 + 1] = v.y;
        tile[r][lc * 4 + 2] = v.z; tile[r][lc * 4 + 3] = v.w;
    }
    __syncthreads();
#pragma unroll
    for (int j = 0; j < 4; j++) {
        int c = (tid >> 4) + j * 16;
        int r = (tid & 15) * 4;
        ushort4 pk;
        pk.x = f2bf(tile[r + 0][c]);
        pk.y = f2bf(tile[r + 1][c]);
        pk.z = f2bf(tile[r + 2][c]);
        pk.w = f2bf(tile[r + 3][c]);
        *(ushort4*)(oute + (size_t)(c0 + c) * R_ + r0 + r) = pk;
    }
}

// ---------------------------------------------------------------- grouped GEMM1
// 256x256 tile, 512 threads (8 waves, 2M x 4N; per-wave 128x64). K-tile 64 in
// two 32-K slices; 4 phases per K-tile. PER-PHASE derived gates (R4 fix):
//   phase 1 reads A(kt)s0 + B(kt)s0: 8 outstanding, need oldest 4 -> vmcnt(4)
//   phase 2 reads B(kt)s0 (3rd-oldest already forced done)      -> vmcnt(6)
//   phase 3 reads A(kt)s1 + B(kt)s1                             -> vmcnt(4)
//   phase 4 reads B(kt)s1                                       -> vmcnt(6)
__global__ __launch_bounds__(512, 2) void moe_gemm1(
    const unsigned short* __restrict__ xb,
    const unsigned short* __restrict__ wg_t,   // [NE][INTER][HID]
    const unsigned short* __restrict__ wu_t,   // [NE][INTER][HID]
    const int* __restrict__ offsets, const int* __restrict__ row_token,
    const int* __restrict__ wl, const int* __restrict__ n_wl,
    unsigned short* __restrict__ h_buf)        // [NROWS][INTER]
{
    if ((int)blockIdx.y >= *n_wl) return;
    int wle = wl[blockIdx.y];
    int e = wle >> 24, row0 = wle & 0xffffff;
    int off = offsets[e], cnt = offsets[e + 1] - off;
    int i0 = blockIdx.x * 128;

    __shared__ __align__(16) unsigned short As[32768];  // 64 KB: [2][2][256][32]
    __shared__ __align__(16) unsigned short Bs[32768];  // 64 KB

    int tid = threadIdx.x, wave = tid >> 6, lane = tid & 63;
    int wm = wave & 1, wn = wave >> 1;
    int l16 = lane & 15, quad = lane >> 4;
    int fsw = (l16 >> 1) & 3;                  // frag-read chunk xor

    int kswz = ((lane & 3) ^ ((lane >> 3) & 3)) * 8;
    int r0s = wave * 32 + (lane >> 2);         // staging row, load j=0
    int r1s = r0s + 16;                        // load j=1

    int gA0 = row0 + r0s, gA1 = row0 + r1s;
    int tok0 = row_token[off + ((gA0 < cnt) ? gA0 : 0)];
    int tok1 = row_token[off + ((gA1 < cnt) ? gA1 : 0)];
    const unsigned short* aptr0 = xb + (size_t)tok0 * HID + kswz;
    const unsigned short* aptr1 = xb + (size_t)tok1 * HID + kswz;

    int ic0 = i0 + (r0s >> 6) * 32 + (r0s & 31);
    int ic1 = i0 + (r1s >> 6) * 32 + (r1s & 31);
    const unsigned short* bptr0 =
        (((r0s >> 5) & 1) ? wu_t : wg_t) + (size_t)e * INTER * HID + (size_t)ic0 * HID + kswz;
    const unsigned short* bptr1 =
        (((r1s >> 5) & 1) ? wu_t : wg_t) + (size_t)e * INTER * HID + (size_t)ic1 * HID + kswz;

    f32x4 acc[8][4];
#pragma unroll
    for (int mi = 0; mi < 8; mi++)
#pragma unroll
        for (int ni = 0; ni < 4; ni++) acc[mi][ni] = {0.f, 0.f, 0.f, 0.f};

    // prologue: stage all 4 halves of K-tile 0 into buf 0, full drain once.
    {
        unsigned short* dA = &As[wave * 1024];
        unsigned short* dB = &Bs[wave * 1024];
        gl2lds16(aptr0, dA);            gl2lds16(aptr1, dA + 512);
        gl2lds16(bptr0, dB);            gl2lds16(bptr1, dB + 512);
        gl2lds16(aptr0 + 32, dA + 8192); gl2lds16(aptr1 + 32, dA + 8192 + 512);
        gl2lds16(bptr0 + 32, dB + 8192); gl2lds16(bptr1 + 32, dB + 8192 + 512);
    }
    __syncthreads();

#pragma unroll 1
    for (int kt = 0; kt < 16; kt++) {
        const unsigned short* Ac = &As[(kt & 1) << 14];
        const unsigned short* Bc = &Bs[(kt & 1) << 14];
        unsigned short* An = &As[(((kt + 1) & 1) << 14) + wave * 1024];
        unsigned short* Bn = &Bs[(((kt + 1) & 1) << 14) + wave * 1024];
        int kb = (kt + 1) * 64;
        bool more = kt < 15;
        bf16x8 a[8], b0, b1;

        // ---------- phase 1: slice 0, ni 0-1; stage A-ks0(kt+1)
        asm volatile("s_waitcnt vmcnt(4)" ::: "memory");
        __builtin_amdgcn_s_barrier();
#pragma unroll
        for (int mi = 0; mi < 8; mi++)
            a[mi] = *(const bf16x8*)&Ac[(wm * 128 + mi * 16 + l16) * 32 + (quad ^ fsw) * 8];
        b0 = *(const bf16x8*)&Bc[(wn * 64 + l16) * 32 + (quad ^ fsw) * 8];
        b1 = *(const bf16x8*)&Bc[(wn * 64 + 16 + l16) * 32 + (quad ^ fsw) * 8];
        if (more) { gl2lds16(aptr0 + kb, An); gl2lds16(aptr1 + kb, An + 512); }
        __builtin_amdgcn_s_setprio(1);
#pragma unroll
        for (int mi = 0; mi < 8; mi++) {
            acc[mi][0] = __builtin_amdgcn_mfma_f32_16x16x32_bf16(a[mi], b0, acc[mi][0], 0, 0, 0);
            acc[mi][1] = __builtin_amdgcn_mfma_f32_16x16x32_bf16(a[mi], b1, acc[mi][1], 0, 0, 0);
        }
        __builtin_amdgcn_s_setprio(0);

        // ---------- phase 2: slice 0, ni 2-3; stage B-ks0(kt+1)
        asm volatile("s_waitcnt vmcnt(6)" ::: "memory");
        __builtin_amdgcn_s_barrier();
        b0 = *(const bf16x8*)&Bc[(wn * 64 + 32 + l16) * 32 + (quad ^ fsw) * 8];
        b1 = *(const bf16x8*)&Bc[(wn * 64 + 48 + l16) * 32 + (quad ^ fsw) * 8];
        if (more) { gl2lds16(bptr0 + kb, Bn); gl2lds16(bptr1 + kb, Bn + 512); }
        __builtin_amdgcn_s_setprio(1);
#pragma unroll
        for (int mi = 0; mi < 8; mi++) {
            acc[mi][2] = __builtin_amdgcn_mfma_f32_16x16x32_bf16(a[mi], b0, acc[mi][2], 0, 0, 0);
            acc[mi][3] = __builtin_amdgcn_mfma_f32_16x16x32_bf16(a[mi], b1, acc[mi][3], 0, 0, 0);
        }
        __builtin_amdgcn_s_setprio(0);

        // ---------- phase 3: slice 1, ni 0-1; stage A-ks1(kt+1)
        asm volatile("s_waitcnt vmcnt(4)" ::: "memory");
        __builtin_amdgcn_s_barrier();
#pragma unroll
        for (int mi = 0; mi < 8; mi++)
            a[mi] = *(const bf16x8*)&Ac[8192 + (wm * 128 + mi * 16 + l16) * 32 + (quad ^ fsw) * 8];
        b0 = *(const bf16x8*)&Bc[8192 + (wn * 64 + l16) * 32 + (quad ^ fsw) * 8];
        b1 = *(const bf16x8*)&Bc[8192 + (wn * 64 + 16 + l16) * 32 + (quad ^ fsw) * 8];
        if (more) { gl2lds16(aptr0 + kb + 32, An + 8192); gl2lds16(aptr1 + kb + 32, An + 8192 + 512); }
        __builtin_amdgcn_s_setprio(1);
#pragma unroll
        for (int mi = 0; mi < 8; mi++) {
            acc[mi][0] = __builtin_amdgcn_mfma_f32_16x16x32_bf16(a[mi], b0, acc[mi][0], 0, 0, 0);
            acc[mi][1] = __builtin_amdgcn_mfma_f32_16x16x32_bf16(a[mi], b1, acc[mi][1], 0, 0, 0);
        }
        __builtin_amdgcn_s_setprio(0);

        // ---------- phase 4: slice 1, ni 2-3; stage B-ks1(kt+1)
        asm volatile("s_waitcnt vmcnt(6)" ::: "memory");
        __builtin_amdgcn_s_barrier();
        b0 = *(const bf16x8*)&Bc[8192 + (wn * 64 + 32 + l16) * 32 + (quad ^ fsw) * 8];
        b1 = *(const bf16x8*)&Bc[8192 + (wn * 64 + 48 + l16) * 32 + (quad ^ fsw) * 8];
        if (more) { gl2lds16(bptr0 + kb + 32, Bn + 8192); gl2lds16(bptr1 + kb + 32, Bn + 8192 + 512); }
        __builtin_amdgcn_s_setprio(1);
#pragma unroll
        for (int mi = 0; mi < 8; mi++) {
            acc[mi][2] = __builtin_amdgcn_mfma_f32_16x16x32_bf16(a[mi], b0, acc[mi][2], 0, 0, 0);
            acc[mi][3] = __builtin_amdgcn_mfma_f32_16x16x32_bf16(a[mi], b1, acc[mi][3], 0, 0, 0);
        }
        __builtin_amdgcn_s_setprio(0);
    }

    // epilogue: silu(g)*u -> bf16  (C/D: col=lane&15, row=quad*4+reg)
#pragma unroll
    for (int mi = 0; mi < 8; mi++)
#pragma unroll
        for (int np = 0; np < 2; np++)
#pragma unroll
            for (int r = 0; r < 4; r++) {
                int ml = wm * 128 + mi * 16 + quad * 4 + r;
                int row = row0 + ml;
                if (row < cnt) {
                    float g = acc[mi][np][r], u = acc[mi][np + 2][r];
                    float hv = (g / (1.f + expf(-g))) * u;
                    h_buf[(size_t)(off + row) * INTER + i0 + wn * 32 + np * 16 + l16] = f2bf(hv);
                }
            }
}

// ---------------------------------------------------------------- grouped GEMM2
// 256 rows x 128 cols, 512 threads (8 waves 2M x 4N; per-wave 128x32).
// 2 phases per K-tile (all ni fit in one phase). Per phase: gate+barrier,
// read a[8]+b0,b1 of one 32-K slice, stage next K-tile's same slice
// (A x2 + B x1 = 3 loads), 16 MFMA. Gate derivation: at each phase gate the
// wave has 6 outstanding loads and reads the oldest 3 -> vmcnt(3) both phases.
// LDS: A [2][2][256][32] 64KB + B [2][2][128][32] 32KB = 96 KB.
__global__ __launch_bounds__(512, 2) void moe_gemm2(
    const unsigned short* __restrict__ h_buf,  // [NROWS][INTER]
    const unsigned short* __restrict__ wd_t,   // [NE][HID][INTER]
    const int* __restrict__ offsets, const float* __restrict__ row_w,
    const int* __restrict__ wl, const int* __restrict__ n_wl,
    unsigned short* __restrict__ y_buf)        // [NROWS][HID]
{
    if ((int)blockIdx.y >= *n_wl) return;
    int wle = wl[blockIdx.y];
    int e = wle >> 24, row0 = wle & 0xffffff;
    int off = offsets[e], cnt = offsets[e + 1] - off;
    int h0 = blockIdx.x * 128;

    __shared__ __align__(16) unsigned short As[32768];  // 64 KB: [2][2][256][32]
    __shared__ __align__(16) unsigned short Bs[16384];  // 32 KB: [2][2][128][32]

    int tid = threadIdx.x, wave = tid >> 6, lane = tid & 63;
    int wm = wave & 1, wn = wave >> 1;
    int l16 = lane & 15, quad = lane >> 4;
    int fsw = (l16 >> 1) & 3;

    int kswz = ((lane & 3) ^ ((lane >> 3) & 3)) * 8;
    int r0s = wave * 32 + (lane >> 2);     // A staging rows (two loads)
    int r1s = r0s + 16;
    int rbs = wave * 16 + (lane >> 2);     // B staging row (one load)

    int gA0 = row0 + r0s, gA1 = row0 + r1s;
    const unsigned short* aptr0 = h_buf + (size_t)(off + ((gA0 < cnt) ? gA0 : 0)) * INTER + kswz;
    const unsigned short* aptr1 = h_buf + (size_t)(off + ((gA1 < cnt) ? gA1 : 0)) * INTER + kswz;
    const unsigned short* bptr  = wd_t + (size_t)e * HID * INTER + (size_t)(h0 + rbs) * INTER + kswz;

    f32x4 acc[8][2];
#pragma unroll
    for (int mi = 0; mi < 8; mi++)
#pragma unroll
        for (int ni = 0; ni < 2; ni++) acc[mi][ni] = {0.f, 0.f, 0.f, 0.f};

    // prologue: stage both slices of K-tile 0 into buf 0 (6 loads), full drain.
    {
        unsigned short* dA = &As[wave * 1024];
        unsigned short* dB = &Bs[wave * 512];
        gl2lds16(aptr0, dA);             gl2lds16(aptr1, dA + 512);
        gl2lds16(bptr, dB);
        gl2lds16(aptr0 + 32, dA + 8192); gl2lds16(aptr1 + 32, dA + 8192 + 512);
        gl2lds16(bptr + 32, dB + 4096);
    }
    __syncthreads();

#pragma unroll 1
    for (int kt = 0; kt < 22; kt++) {
        const unsigned short* Ac = &As[(kt & 1) << 14];
        const unsigned short* Bc = &Bs[(kt & 1) << 13];
        unsigned short* An = &As[(((kt + 1) & 1) << 14) + wave * 1024];
        unsigned short* Bn = &Bs[(((kt + 1) & 1) << 13) + wave * 512];
        int kb = (kt + 1) * 64;
        bool more = kt < 21;
        bf16x8 a[8], b0, b1;

        // ---------- phase 1: slice 0, all ni; stage slice-0(kt+1): A x2 + B x1
        asm volatile("s_waitcnt vmcnt(3)" ::: "memory");
        __builtin_amdgcn_s_barrier();
#pragma unroll
        for (int mi = 0; mi < 8; mi++)
            a[mi] = *(const bf16x8*)&Ac[(wm * 128 + mi * 16 + l16) * 32 + (quad ^ fsw) * 8];
        b0 = *(const bf16x8*)&Bc[(wn * 32 + l16) * 32 + (quad ^ fsw) * 8];
        b1 = *(const bf16x8*)&Bc[(wn * 32 + 16 + l16) * 32 + (quad ^ fsw) * 8];
        if (more) {
            gl2lds16(aptr0 + kb, An); gl2lds16(aptr1 + kb, An + 512);
            gl2lds16(bptr + kb, Bn);
        }
        __builtin_amdgcn_s_setprio(1);
#pragma unroll
        for (int mi = 0; mi < 8; mi++) {
            acc[mi][0] = __builtin_amdgcn_mfma_f32_16x16x32_bf16(a[mi], b0, acc[mi][0], 0, 0, 0);
            acc[mi][1] = __builtin_amdgcn_mfma_f32_16x16x32_bf16(a[mi], b1, acc[mi][1], 0, 0, 0);
        }
        __builtin_amdgcn_s_setprio(0);

        // ---------- phase 2: slice 1, all ni; stage slice-1(kt+1): A x2 + B x1
        asm volatile("s_waitcnt vmcnt(3)" ::: "memory");
        __builtin_amdgcn_s_barrier();
#pragma unroll
        for (int mi = 0; mi < 8; mi++)
            a[mi] = *(const bf16x8*)&Ac[8192 + (wm * 128 + mi * 16 + l16) * 32 + (quad ^ fsw) * 8];
        b0 = *(const bf16x8*)&Bc[4096 + (wn * 32 + l16) * 32 + (quad ^ fsw) * 8];
        b1 = *(const bf16x8*)&Bc[4096 + (wn * 32 + 16 + l16) * 32 + (quad ^ fsw) * 8];
        if (more) {
            gl2lds16(aptr0 + kb + 32, An + 8192); gl2lds16(aptr1 + kb + 32, An + 8192 + 512);
            gl2lds16(bptr + kb + 32, Bn + 4096);
        }
        __builtin_amdgcn_s_setprio(1);
#pragma unroll
        for (int mi = 0; mi < 8; mi++) {
            acc[mi][0] = __builtin_amdgcn_mfma_f32_16x16x32_bf16(a[mi], b0, acc[mi][0], 0, 0, 0);
            acc[mi][1] = __builtin_amdgcn_mfma_f32_16x16x32_bf16(a[mi], b1, acc[mi][1], 0, 0, 0);
        }
        __builtin_amdgcn_s_setprio(0);
    }

    // epilogue: scale by row_w -> bf16  (C/D: col=lane&15, row=quad*4+reg)
#pragma unroll
    for (int mi = 0; mi < 8; mi++)
#pragma unroll
        for (int ni = 0; ni < 2; ni++)
#pragma unroll
            for (int r = 0; r < 4; r++) {
                int ml = wm * 128 + mi * 16 + quad * 4 + r;
                int row = row0 + ml;
                if (row < cnt) {
                    float w = row_w[off + row];
                    y_buf[(size_t)(off + row) * HID + h0 + wn * 32 + ni * 16 + l16] =
                        f2bf(acc[mi][ni][r] * w);
                }
            }
}

// ---------------------------------------------------------------- combine
__global__ __launch_bounds__(256) void moe_combine(
    const unsigned short* __restrict__ y_buf, const int* __restrict__ tok_rows,
    float* __restrict__ out)
{
    int gid = blockIdx.x * 256 + threadIdx.x;   // T*H/8 threads
    int t = gid >> 7;
    int c = gid & 127;
    u32x4 a = *(const u32x4*)(y_buf + (size_t)tok_rows[2 * t]     * HID + c * 8);
    u32x4 b = *(const u32x4*)(y_buf + (size_t)tok_rows[2 * t + 1] * HID + c * 8);
    float res[8];
#pragma unroll
    for (int j = 0; j < 4; j++) {
        unsigned int wa = a[j], wb = b[j];
        res[2 * j]     = __builtin_bit_cast(float, wa << 16)
                       + __builtin_bit_cast(float, wb << 16);
        res[2 * j + 1] = __builtin_bit_cast(float, wa & 0xffff0000u)
                       + __builtin_bit_cast(float, wb & 0xffff0000u);
    }
    float* o = out + (size_t)t * HID + c * 8;
    *(float4*)(o)     = make_float4(res[0], res[1], res[2], res[3]);
    *(float4*)(o + 4) = make_float4(res[4], res[5], res[6], res[7]);
}

// ---------------------------------------------------------------- launch
extern "C" void kernel_launch(void* const* d_in, const int* in_sizes, int n_in,
                              void* d_out, int out_size, void* d_ws, size_t ws_size,
                              hipStream_t stream)
{
    const float* x      = (const float*)d_in[0];
    const float* gate_w = (const float*)d_in[1];
    const float* w_gate = (const float*)d_in[2];
    const float* w_up   = (const float*)d_in[3];
    const float* w_down = (const float*)d_in[4];
    float* out = (float*)d_out;                    // final [T,H] ++ logits [T,E]
    float* logits_out = out + (size_t)T_TOK * HID;

    char* ws = (char*)d_ws;
    int*   offsets    = (int*)(ws + 0);                  // 9 ints
    int*   n_wl256    = (int*)(ws + 68);
    int*   wl256      = (int*)(ws + 704);                // MAXWL256 ints (288 B)
    int*   hist_g     = (int*)(ws + 1024);               // RBLK*NE = 8 KB
    int*   block_base = (int*)(ws + 1024 + 8192);        // 8 KB
    int*   topk_idx   = (int*)(ws + 32768);                       // 64 KB
    float* topk_w     = (float*)(ws + 32768 + 65536);             // 64 KB
    int*   row_token  = (int*)(ws + 32768 + 2 * 65536);           // 64 KB
    float* row_w      = (float*)(ws + 32768 + 3 * 65536);         // 64 KB
    int*   tok_rows   = (int*)(ws + 32768 + 4 * 65536);           // 64 KB
    size_t o = 32768 + 5 * (size_t)65536 + 32768;        // 393216
    unsigned short* xb   = (unsigned short*)(ws + o); o += (size_t)T_TOK * HID * 2;
    unsigned short* wg_t = (unsigned short*)(ws + o); o += (size_t)NE * INTER * HID * 2;
    unsigned short* wu_t = (unsigned short*)(ws + o); o += (size_t)NE * INTER * HID * 2;
    unsigned short* wd_t = (unsigned short*)(ws + o); o += (size_t)NE * HID * INTER * 2;
    unsigned short* h_buf = (unsigned short*)(ws + o); o += (size_t)NROWS * INTER * 2;
    unsigned short* y_buf = (unsigned short*)(ws + o); o += (size_t)NROWS * HID * 2;

    moe_router<<<RBLK, 256, 0, stream>>>(x, gate_w, xb, logits_out,
                                         topk_idx, topk_w, hist_g);
    moe_scan<<<1, 256, 0, stream>>>(hist_g, offsets, block_base, wl256, n_wl256);
    moe_scatter<<<RBLK, 64, 0, stream>>>(topk_idx, topk_w, block_base,
                                         row_token, row_w, tok_rows);
    moe_transpose_all<<<dim3(352, 24), 256, 0, stream>>>(
        w_gate, w_up, w_down, wg_t, wu_t, wd_t);

    moe_gemm1<<<dim3(GX1, MAXWL256), 512, 0, stream>>>(
        xb, wg_t, wu_t, offsets, row_token, wl256, n_wl256, h_buf);
    moe_gemm2<<<dim3(GX2, MAXWL256), 512, 0, stream>>>(
        h_buf, wd_t, offsets, row_w, wl256, n_wl256, y_buf);
    moe_combine<<<(T_TOK * HID / 8) / 256, 256, 0, stream>>>(y_buf, tok_rows, out);
}

// Round 8
// 433.002 us; speedup vs baseline: 1.0698x; 1.0147x over previous
//
#include <hip/hip_runtime.h>
#include <hip/hip_bf16.h>
#include <math.h>

// Problem constants (from reference)
#define T_TOK 8192            // B*S = 4*2048
#define HID   1024
#define NE    8
#define TOPKN 2
#define INTER 1408
#define NROWS (T_TOK*TOPKN)   // 16384 routed (token,expert) rows
#define MAXWL256 72           // max 256-row worklist entries (gemm1)
#define MAXWL128 144          // max 128-row worklist entries (gemm2)
#define RBLK  256             // router blocks (32 tokens each)
#define GX1   (INTER/128)     // gemm1 grid.x = 11
#define GX2   (HID/128)       // gemm2 grid.x = 8
#define NTRT  8448            // transpose tiles: 24 (m,e) x 352

typedef __attribute__((ext_vector_type(8))) __bf16 bf16x8;
typedef __attribute__((ext_vector_type(4))) float f32x4;
typedef __attribute__((ext_vector_type(4))) unsigned int u32x4;

__device__ __forceinline__ unsigned short f2bf(float f) {
    unsigned int u = __builtin_bit_cast(unsigned int, f);
    unsigned int lsb = (u >> 16) & 1u;
    u += 0x7fffu + lsb;            // round-to-nearest-even
    return (unsigned short)(u >> 16);
}

// async global->LDS, 16B per lane (m97 pattern).
__device__ __forceinline__ void gl2lds16(const void* g, void* l) {
    __builtin_amdgcn_global_load_lds(
        (const __attribute__((address_space(1))) unsigned int*)g,
        (__attribute__((address_space(3))) unsigned int*)l, 16, 0, 0);
}

// ---------------------------------------------------------------- pre (router + weight transpose, fused)
__global__ __launch_bounds__(256) void moe_pre(
    const float* __restrict__ x, const float* __restrict__ gate_w,
    const float* __restrict__ w_gate, const float* __restrict__ w_up,
    const float* __restrict__ w_down,
    unsigned short* __restrict__ xb, float* __restrict__ logits_out,
    int* __restrict__ topk_idx, float* __restrict__ topk_w,
    int* __restrict__ hist_g,
    unsigned short* __restrict__ wg_t, unsigned short* __restrict__ wu_t,
    unsigned short* __restrict__ wd_t)
{
    __shared__ float smem[64 * 65];
    int tid = threadIdx.x;

    if ((int)blockIdx.x < RBLK) {
        // ---------------- router body ----------------
        int* lh = (int*)smem;
        int wave = tid >> 6, lane = tid & 63;
        if (tid < NE) lh[tid] = 0;
        __syncthreads();
#pragma unroll 1
        for (int i = 0; i < 8; i++) {
            int t = blockIdx.x * 32 + wave * 8 + i;
            const float4* xr = (const float4*)(x + (size_t)t * HID);
            float acc[NE];
#pragma unroll
            for (int e = 0; e < NE; e++) acc[e] = 0.f;
#pragma unroll
            for (int j = 0; j < 4; j++) {
                float4 xv = xr[j * 64 + lane];
                ushort4 pk;
                pk.x = f2bf(xv.x); pk.y = f2bf(xv.y);
                pk.z = f2bf(xv.z); pk.w = f2bf(xv.w);
                *(ushort4*)(xb + (size_t)t * HID + j * 256 + lane * 4) = pk;
#pragma unroll
                for (int e = 0; e < NE; e++) {
                    float4 gv = *(const float4*)(gate_w + e * HID + j * 256 + lane * 4);
                    acc[e] += xv.x * gv.x + xv.y * gv.y + xv.z * gv.z + xv.w * gv.w;
                }
            }
#pragma unroll
            for (int e = 0; e < NE; e++) {
                float v = acc[e];
#pragma unroll
                for (int off = 32; off; off >>= 1) v += __shfl_xor(v, off, 64);
                acc[e] = v;
            }
            if (lane == 0) {
                float m = acc[0];
#pragma unroll
                for (int e = 1; e < NE; e++) m = fmaxf(m, acc[e]);
                float p[NE]; float s = 0.f;
#pragma unroll
                for (int e = 0; e < NE; e++) { p[e] = expf(acc[e] - m); s += p[e]; }
                float inv = 1.f / s;
#pragma unroll
                for (int e = 0; e < NE; e++) logits_out[(size_t)t * NE + e] = acc[e];
                int i0 = 0;
#pragma unroll
                for (int e = 1; e < NE; e++) if (p[e] > p[i0]) i0 = e;
                int i1 = (i0 == 0) ? 1 : 0;
#pragma unroll
                for (int e = 0; e < NE; e++) if (e != i0 && p[e] > p[i1]) i1 = e;
                topk_idx[2 * t]     = i0; topk_w[2 * t]     = p[i0] * inv;
                topk_idx[2 * t + 1] = i1; topk_w[2 * t + 1] = p[i1] * inv;
                atomicAdd(&lh[i0], 1);
                atomicAdd(&lh[i1], 1);
            }
        }
        __syncthreads();
        if (tid < NE) hist_g[blockIdx.x * NE + tid] = lh[tid];
    } else {
        // ---------------- transpose body ----------------
        int tz = (int)blockIdx.x - RBLK;
        int z = tz / 352, txy = tz % 352;
        int m = z >> 3, e = z & 7;
        const float* in; unsigned short* out; int R_, C_;
        if (m == 0)      { in = w_gate; out = wg_t; R_ = HID;   C_ = INTER; }
        else if (m == 1) { in = w_up;   out = wu_t; R_ = HID;   C_ = INTER; }
        else             { in = w_down; out = wd_t; R_ = INTER; C_ = HID;   }
        int ntx = C_ >> 6;
        int bx = txy % ntx, by = txy / ntx;
        const float* ine = in + (size_t)e * R_ * C_;
        unsigned short* oute = out + (size_t)e * R_ * C_;
        int c0 = bx * 64, r0 = by * 64;
        int lr = tid >> 4;          // 0..15
        int lc = tid & 15;          // float4 column chunk
#pragma unroll
        for (int j = 0; j < 4; j++) {
            int r = lr + j * 16;
            float4 v = *(const float4*)(ine + (size_t)(r0 + r) * C_ + c0 + lc * 4);
            smem[r * 65 + lc * 4 + 0] = v.x; smem[r * 65 + lc * 4 + 1] = v.y;
            smem[r * 65 + lc * 4 + 2] = v.z; smem[r * 65 + lc * 4 + 3] = v.w;
        }
        __syncthreads();
#pragma unroll
        for (int j = 0; j < 4; j++) {
            int c = (tid >> 4) + j * 16;
            int r = (tid & 15) * 4;
            ushort4 pk;
            pk.x = f2bf(smem[(r + 0) * 65 + c]);
            pk.y = f2bf(smem[(r + 1) * 65 + c]);
            pk.z = f2bf(smem[(r + 2) * 65 + c]);
            pk.w = f2bf(smem[(r + 3) * 65 + c]);
            *(ushort4*)(oute + (size_t)(c0 + c) * R_ + r0 + r) = pk;
        }
    }
}

// ---------------------------------------------------------------- scan
__global__ __launch_bounds__(256) void moe_scan(
    const int* __restrict__ hist_g, int* __restrict__ offsets,
    int* __restrict__ block_base,
    int* __restrict__ wl256, int* __restrict__ n_wl256,
    int* __restrict__ wl128, int* __restrict__ n_wl128)
{
    __shared__ int h[RBLK * NE];
    __shared__ int cnt[NE], offs[NE];
    int tid = threadIdx.x;
    for (int i = tid; i < RBLK * NE; i += 256) h[i] = hist_g[i];
    __syncthreads();
    {
        int e = tid >> 5, g = tid & 31;
        int s = 0;
        for (int b = g; b < RBLK; b += 32) s += h[b * NE + e];
#pragma unroll
        for (int off2 = 16; off2; off2 >>= 1) s += __shfl_xor(s, off2, 32);
        if (g == 0) cnt[e] = s;
    }
    __syncthreads();
    if (tid == 0) {
        int s = 0;
        for (int e = 0; e < NE; e++) { offs[e] = s; offsets[e] = s; s += cnt[e]; }
        offsets[NE] = s;
        int n2 = 0;
        for (int e = 0; e < NE; e++)
            for (int r0 = 0; r0 < cnt[e]; r0 += 256)
                wl256[n2++] = (e << 24) | r0;
        *n_wl256 = n2;
        int n1 = 0;
        for (int e = 0; e < NE; e++)
            for (int r0 = 0; r0 < cnt[e]; r0 += 128)
                wl128[n1++] = (e << 24) | r0;
        *n_wl128 = n1;
    }
    __syncthreads();
    if (tid < NE) {
        int run = offs[tid];
        for (int b = 0; b < RBLK; b++) {
            block_base[b * NE + tid] = run;
            run += h[b * NE + tid];
        }
    }
}

// ---------------------------------------------------------------- scatter
__global__ __launch_bounds__(64) void moe_scatter(
    const int* __restrict__ topk_idx, const float* __restrict__ topk_w,
    const int* __restrict__ block_base, int* __restrict__ row_token,
    float* __restrict__ row_w, int* __restrict__ tok_rows)
{
    __shared__ int base[NE];
    int tid = threadIdx.x;
    if (tid < NE) base[tid] = block_base[blockIdx.x * NE + tid];
    __syncthreads();
    int idx = blockIdx.x * 64 + tid;     // = 2*t + k
    int e = topk_idx[idx];
    int pos = atomicAdd(&base[e], 1);    // LDS atomic
    row_token[pos] = idx >> 1;
    row_w[pos] = topk_w[idx];
    tok_rows[idx] = pos;
}

// ---------------------------------------------------------------- grouped GEMM1
// 256x256 tile, 512 threads. 4 phases/K-tile, steady gates vmcnt(4)/(6)/(4)/(6).
// FINAL K-TILE IS PEELED (R7 fix): in the last iteration nothing new is staged,
// so the counted gates stop protecting the newest slice (vmcnt(4) at ph3 was a
// no-op on exactly the data being read -> latent race since R2). Tail does one
// vmcnt(0)+barrier (each wave drains its own loads -> collective residency),
// then computes both slices with no further barriers.
__global__ __launch_bounds__(512, 2) void moe_gemm1(
    const unsigned short* __restrict__ xb,
    const unsigned short* __restrict__ wg_t,   // [NE][INTER][HID]
    const unsigned short* __restrict__ wu_t,   // [NE][INTER][HID]
    const int* __restrict__ offsets, const int* __restrict__ row_token,
    const int* __restrict__ wl, const int* __restrict__ n_wl,
    unsigned short* __restrict__ h_buf)        // [NROWS][INTER]
{
    if ((int)blockIdx.y >= *n_wl) return;
    int wle = wl[blockIdx.y];
    int e = wle >> 24, row0 = wle & 0xffffff;
    int off = offsets[e], cnt = offsets[e + 1] - off;
    int i0 = blockIdx.x * 128;

    __shared__ __align__(16) unsigned short As[32768];  // 64 KB: [2][2][256][32]
    __shared__ __align__(16) unsigned short Bs[32768];  // 64 KB

    int tid = threadIdx.x, wave = tid >> 6, lane = tid & 63;
    int wm = wave & 1, wn = wave >> 1;
    int l16 = lane & 15, quad = lane >> 4;
    int fsw = (l16 >> 1) & 3;                  // frag-read chunk xor

    int kswz = ((lane & 3) ^ ((lane >> 3) & 3)) * 8;
    int r0s = wave * 32 + (lane >> 2);         // staging row, load j=0
    int r1s = r0s + 16;                        // load j=1

    int gA0 = row0 + r0s, gA1 = row0 + r1s;
    int tok0 = row_token[off + ((gA0 < cnt) ? gA0 : 0)];
    int tok1 = row_token[off + ((gA1 < cnt) ? gA1 : 0)];
    const unsigned short* aptr0 = xb + (size_t)tok0 * HID + kswz;
    const unsigned short* aptr1 = xb + (size_t)tok1 * HID + kswz;

    int ic0 = i0 + (r0s >> 6) * 32 + (r0s & 31);
    int ic1 = i0 + (r1s >> 6) * 32 + (r1s & 31);
    const unsigned short* bptr0 =
        (((r0s >> 5) & 1) ? wu_t : wg_t) + (size_t)e * INTER * HID + (size_t)ic0 * HID + kswz;
    const unsigned short* bptr1 =
        (((r1s >> 5) & 1) ? wu_t : wg_t) + (size_t)e * INTER * HID + (size_t)ic1 * HID + kswz;

    f32x4 acc[8][4];
#pragma unroll
    for (int mi = 0; mi < 8; mi++)
#pragma unroll
        for (int ni = 0; ni < 4; ni++) acc[mi][ni] = {0.f, 0.f, 0.f, 0.f};

    // prologue: stage all 4 halves of K-tile 0 into buf 0, full drain once.
    {
        unsigned short* dA = &As[wave * 1024];
        unsigned short* dB = &Bs[wave * 1024];
        gl2lds16(aptr0, dA);            gl2lds16(aptr1, dA + 512);
        gl2lds16(bptr0, dB);            gl2lds16(bptr1, dB + 512);
        gl2lds16(aptr0 + 32, dA + 8192); gl2lds16(aptr1 + 32, dA + 8192 + 512);
        gl2lds16(bptr0 + 32, dB + 8192); gl2lds16(bptr1 + 32, dB + 8192 + 512);
    }
    __syncthreads();

#pragma unroll 1
    for (int kt = 0; kt < 15; kt++) {          // peeled: loop stages kt+1 always
        const unsigned short* Ac = &As[(kt & 1) << 14];
        const unsigned short* Bc = &Bs[(kt & 1) << 14];
        unsigned short* An = &As[(((kt + 1) & 1) << 14) + wave * 1024];
        unsigned short* Bn = &Bs[(((kt + 1) & 1) << 14) + wave * 1024];
        int kb = (kt + 1) * 64;
        bf16x8 a[8], b0, b1;

        // ---------- phase 1: slice 0, ni 0-1; stage A-ks0(kt+1)
        asm volatile("s_waitcnt vmcnt(4)" ::: "memory");
        __builtin_amdgcn_s_barrier();
#pragma unroll
        for (int mi = 0; mi < 8; mi++)
            a[mi] = *(const bf16x8*)&Ac[(wm * 128 + mi * 16 + l16) * 32 + (quad ^ fsw) * 8];
        b0 = *(const bf16x8*)&Bc[(wn * 64 + l16) * 32 + (quad ^ fsw) * 8];
        b1 = *(const bf16x8*)&Bc[(wn * 64 + 16 + l16) * 32 + (quad ^ fsw) * 8];
        gl2lds16(aptr0 + kb, An); gl2lds16(aptr1 + kb, An + 512);
        __builtin_amdgcn_s_setprio(1);
#pragma unroll
        for (int mi = 0; mi < 8; mi++) {
            acc[mi][0] = __builtin_amdgcn_mfma_f32_16x16x32_bf16(a[mi], b0, acc[mi][0], 0, 0, 0);
            acc[mi][1] = __builtin_amdgcn_mfma_f32_16x16x32_bf16(a[mi], b1, acc[mi][1], 0, 0, 0);
        }
        __builtin_amdgcn_s_setprio(0);

        // ---------- phase 2: slice 0, ni 2-3; stage B-ks0(kt+1)
        asm volatile("s_waitcnt vmcnt(6)" ::: "memory");
        __builtin_amdgcn_s_barrier();
        b0 = *(const bf16x8*)&Bc[(wn * 64 + 32 + l16) * 32 + (quad ^ fsw) * 8];
        b1 = *(const bf16x8*)&Bc[(wn * 64 + 48 + l16) * 32 + (quad ^ fsw) * 8];
        gl2lds16(bptr0 + kb, Bn); gl2lds16(bptr1 + kb, Bn + 512);
        __builtin_amdgcn_s_setprio(1);
#pragma unroll
        for (int mi = 0; mi < 8; mi++) {
            acc[mi][2] = __builtin_amdgcn_mfma_f32_16x16x32_bf16(a[mi], b0, acc[mi][2], 0, 0, 0);
            acc[mi][3] = __builtin_amdgcn_mfma_f32_16x16x32_bf16(a[mi], b1, acc[mi][3], 0, 0, 0);
        }
        __builtin_amdgcn_s_setprio(0);

        // ---------- phase 3: slice 1, ni 0-1; stage A-ks1(kt+1)
        asm volatile("s_waitcnt vmcnt(4)" ::: "memory");
        __builtin_amdgcn_s_barrier();
#pragma unroll
        for (int mi = 0; mi < 8; mi++)
            a[mi] = *(const bf16x8*)&Ac[8192 + (wm * 128 + mi * 16 + l16) * 32 + (quad ^ fsw) * 8];
        b0 = *(const bf16x8*)&Bc[8192 + (wn * 64 + l16) * 32 + (quad ^ fsw) * 8];
        b1 = *(const bf16x8*)&Bc[8192 + (wn * 64 + 16 + l16) * 32 + (quad ^ fsw) * 8];
        gl2lds16(aptr0 + kb + 32, An + 8192); gl2lds16(aptr1 + kb + 32, An + 8192 + 512);
        __builtin_amdgcn_s_setprio(1);
#pragma unroll
        for (int mi = 0; mi < 8; mi++) {
            acc[mi][0] = __builtin_amdgcn_mfma_f32_16x16x32_bf16(a[mi], b0, acc[mi][0], 0, 0, 0);
            acc[mi][1] = __builtin_amdgcn_mfma_f32_16x16x32_bf16(a[mi], b1, acc[mi][1], 0, 0, 0);
        }
        __builtin_amdgcn_s_setprio(0);

        // ---------- phase 4: slice 1, ni 2-3; stage B-ks1(kt+1)
        asm volatile("s_waitcnt vmcnt(6)" ::: "memory");
        __builtin_amdgcn_s_barrier();
        b0 = *(const bf16x8*)&Bc[8192 + (wn * 64 + 32 + l16) * 32 + (quad ^ fsw) * 8];
        b1 = *(const bf16x8*)&Bc[8192 + (wn * 64 + 48 + l16) * 32 + (quad ^ fsw) * 8];
        gl2lds16(bptr0 + kb + 32, Bn + 8192); gl2lds16(bptr1 + kb + 32, Bn + 8192 + 512);
        __builtin_amdgcn_s_setprio(1);
#pragma unroll
        for (int mi = 0; mi < 8; mi++) {
            acc[mi][2] = __builtin_amdgcn_mfma_f32_16x16x32_bf16(a[mi], b0, acc[mi][2], 0, 0, 0);
            acc[mi][3] = __builtin_amdgcn_mfma_f32_16x16x32_bf16(a[mi], b1, acc[mi][3], 0, 0, 0);
        }
        __builtin_amdgcn_s_setprio(0);
    }

    // ---------- peeled tail: K-tile 15 (buf 1), full drain, no staging.
    {
        const unsigned short* Ac = &As[1 << 14];
        const unsigned short* Bc = &Bs[1 << 14];
        asm volatile("s_waitcnt vmcnt(0)" ::: "memory");
        __builtin_amdgcn_s_barrier();
        bf16x8 a[8], b0, b1;
#pragma unroll
        for (int sl = 0; sl < 2; sl++) {
            int so = sl * 8192;
#pragma unroll
            for (int mi = 0; mi < 8; mi++)
                a[mi] = *(const bf16x8*)&Ac[so + (wm * 128 + mi * 16 + l16) * 32 + (quad ^ fsw) * 8];
            b0 = *(const bf16x8*)&Bc[so + (wn * 64 + l16) * 32 + (quad ^ fsw) * 8];
            b1 = *(const bf16x8*)&Bc[so + (wn * 64 + 16 + l16) * 32 + (quad ^ fsw) * 8];
#pragma unroll
            for (int mi = 0; mi < 8; mi++) {
                acc[mi][0] = __builtin_amdgcn_mfma_f32_16x16x32_bf16(a[mi], b0, acc[mi][0], 0, 0, 0);
                acc[mi][1] = __builtin_amdgcn_mfma_f32_16x16x32_bf16(a[mi], b1, acc[mi][1], 0, 0, 0);
            }
            b0 = *(const bf16x8*)&Bc[so + (wn * 64 + 32 + l16) * 32 + (quad ^ fsw) * 8];
            b1 = *(const bf16x8*)&Bc[so + (wn * 64 + 48 + l16) * 32 + (quad ^ fsw) * 8];
#pragma unroll
            for (int mi = 0; mi < 8; mi++) {
                acc[mi][2] = __builtin_amdgcn_mfma_f32_16x16x32_bf16(a[mi], b0, acc[mi][2], 0, 0, 0);
                acc[mi][3] = __builtin_amdgcn_mfma_f32_16x16x32_bf16(a[mi], b1, acc[mi][3], 0, 0, 0);
            }
        }
    }

    // epilogue: silu(g)*u -> bf16  (C/D: col=lane&15, row=quad*4+reg)
#pragma unroll
    for (int mi = 0; mi < 8; mi++)
#pragma unroll
        for (int np = 0; np < 2; np++)
#pragma unroll
            for (int r = 0; r < 4; r++) {
                int ml = wm * 128 + mi * 16 + quad * 4 + r;
                int row = row0 + ml;
                if (row < cnt) {
                    float g = acc[mi][np][r], u = acc[mi][np + 2][r];
                    float hv = (g / (1.f + expf(-g))) * u;
                    h_buf[(size_t)(off + row) * INTER + i0 + wn * 32 + np * 16 + l16] = f2bf(hv);
                }
            }
}

// ---------------------------------------------------------------- grouped GEMM2
// 128x128 tile, 256 threads (4 waves 2M x 2N; per-wave 64x64). LDS 64 KB ->
// 2 blocks/CU. 2 phases per K-tile (one 32-K slice each), stage next tile's
// same slice (4 loads/phase), gate vmcnt(4) (8 outstanding, need oldest 4).
// Final K-tile peeled with vmcnt(0)+barrier (same tail-race fix as gemm1).
__global__ __launch_bounds__(256, 2) void moe_gemm2(
    const unsigned short* __restrict__ h_buf,  // [NROWS][INTER]
    const unsigned short* __restrict__ wd_t,   // [NE][HID][INTER]
    const int* __restrict__ offsets, const float* __restrict__ row_w,
    const int* __restrict__ wl, const int* __restrict__ n_wl,
    unsigned short* __restrict__ y_buf)        // [NROWS][HID]
{
    if ((int)blockIdx.y >= *n_wl) return;
    int wle = wl[blockIdx.y];
    int e = wle >> 24, row0 = wle & 0xffffff;
    int off = offsets[e], cnt = offsets[e + 1] - off;
    int h0 = blockIdx.x * 128;

    __shared__ __align__(16) unsigned short As[16384];  // 32 KB: [2][2][128][32]
    __shared__ __align__(16) unsigned short Bs[16384];  // 32 KB

    int tid = threadIdx.x, wave = tid >> 6, lane = tid & 63;
    int wm = wave & 1, wn = wave >> 1;       // 2x2 waves
    int l16 = lane & 15, quad = lane >> 4;
    int fsw = (l16 >> 1) & 3;

    int kswz = ((lane & 3) ^ ((lane >> 3) & 3)) * 8;
    int r0s = wave * 16 + (lane >> 2);       // staging rows 0..63 (load j=0)
    int r1s = r0s + 64;                      // rows 64..127 (load j=1)

    int gA0 = row0 + r0s, gA1 = row0 + r1s;
    const unsigned short* aptr0 = h_buf + (size_t)(off + ((gA0 < cnt) ? gA0 : 0)) * INTER + kswz;
    const unsigned short* aptr1 = h_buf + (size_t)(off + ((gA1 < cnt) ? gA1 : 0)) * INTER + kswz;
    const unsigned short* bptr0 = wd_t + (size_t)e * HID * INTER + (size_t)(h0 + r0s) * INTER + kswz;
    const unsigned short* bptr1 = wd_t + (size_t)e * HID * INTER + (size_t)(h0 + r1s) * INTER + kswz;

    f32x4 acc[4][4];
#pragma unroll
    for (int mi = 0; mi < 4; mi++)
#pragma unroll
        for (int ni = 0; ni < 4; ni++) acc[mi][ni] = {0.f, 0.f, 0.f, 0.f};

    // prologue: stage both slices of K-tile 0 into buf 0 (8 loads), full drain.
    {
        unsigned short* dA = &As[wave * 512];
        unsigned short* dB = &Bs[wave * 512];
        gl2lds16(aptr0, dA);             gl2lds16(aptr1, dA + 2048);
        gl2lds16(bptr0, dB);             gl2lds16(bptr1, dB + 2048);
        gl2lds16(aptr0 + 32, dA + 4096); gl2lds16(aptr1 + 32, dA + 4096 + 2048);
        gl2lds16(bptr0 + 32, dB + 4096); gl2lds16(bptr1 + 32, dB + 4096 + 2048);
    }
    __syncthreads();

#pragma unroll 1
    for (int kt = 0; kt < 21; kt++) {          // peeled: loop stages kt+1 always
        const unsigned short* Ac = &As[(kt & 1) << 13];
        const unsigned short* Bc = &Bs[(kt & 1) << 13];
        unsigned short* An = &As[(((kt + 1) & 1) << 13) + wave * 512];
        unsigned short* Bn = &Bs[(((kt + 1) & 1) << 13) + wave * 512];
        int kb = (kt + 1) * 64;
        bf16x8 a[4], b[4];

        // ---------- phase 1: slice 0; stage slice-0(kt+1): A x2 + B x2
        asm volatile("s_waitcnt vmcnt(4)" ::: "memory");
        __builtin_amdgcn_s_barrier();
#pragma unroll
        for (int mi = 0; mi < 4; mi++)
            a[mi] = *(const bf16x8*)&Ac[(wm * 64 + mi * 16 + l16) * 32 + (quad ^ fsw) * 8];
#pragma unroll
        for (int ni = 0; ni < 4; ni++)
            b[ni] = *(const bf16x8*)&Bc[(wn * 64 + ni * 16 + l16) * 32 + (quad ^ fsw) * 8];
        gl2lds16(aptr0 + kb, An); gl2lds16(aptr1 + kb, An + 2048);
        gl2lds16(bptr0 + kb, Bn); gl2lds16(bptr1 + kb, Bn + 2048);
        __builtin_amdgcn_s_setprio(1);
#pragma unroll
        for (int mi = 0; mi < 4; mi++)
#pragma unroll
            for (int ni = 0; ni < 4; ni++)
                acc[mi][ni] = __builtin_amdgcn_mfma_f32_16x16x32_bf16(a[mi], b[ni], acc[mi][ni], 0, 0, 0);
        __builtin_amdgcn_s_setprio(0);

        // ---------- phase 2: slice 1; stage slice-1(kt+1): A x2 + B x2
        asm volatile("s_waitcnt vmcnt(4)" ::: "memory");
        __builtin_amdgcn_s_barrier();
#pragma unroll
        for (int mi = 0; mi < 4; mi++)
            a[mi] = *(const bf16x8*)&Ac[4096 + (wm * 64 + mi * 16 + l16) * 32 + (quad ^ fsw) * 8];
#pragma unroll
        for (int ni = 0; ni < 4; ni++)
            b[ni] = *(const bf16x8*)&Bc[4096 + (wn * 64 + ni * 16 + l16) * 32 + (quad ^ fsw) * 8];
        gl2lds16(aptr0 + kb + 32, An + 4096); gl2lds16(aptr1 + kb + 32, An + 4096 + 2048);
        gl2lds16(bptr0 + kb + 32, Bn + 4096); gl2lds16(bptr1 + kb + 32, Bn + 4096 + 2048);
        __builtin_amdgcn_s_setprio(1);
#pragma unroll
        for (int mi = 0; mi < 4; mi++)
#pragma unroll
            for (int ni = 0; ni < 4; ni++)
                acc[mi][ni] = __builtin_amdgcn_mfma_f32_16x16x32_bf16(a[mi], b[ni], acc[mi][ni], 0, 0, 0);
        __builtin_amdgcn_s_setprio(0);
    }

    // ---------- peeled tail: K-tile 21 (buf 1), full drain, no staging.
    {
        const unsigned short* Ac = &As[1 << 13];
        const unsigned short* Bc = &Bs[1 << 13];
        asm volatile("s_waitcnt vmcnt(0)" ::: "memory");
        __builtin_amdgcn_s_barrier();
        bf16x8 a[4], b[4];
#pragma unroll
        for (int sl = 0; sl < 2; sl++) {
            int so = sl * 4096;
#pragma unroll
            for (int mi = 0; mi < 4; mi++)
                a[mi] = *(const bf16x8*)&Ac[so + (wm * 64 + mi * 16 + l16) * 32 + (quad ^ fsw) * 8];
#pragma unroll
            for (int ni = 0; ni < 4; ni++)
                b[ni] = *(const bf16x8*)&Bc[so + (wn * 64 + ni * 16 + l16) * 32 + (quad ^ fsw) * 8];
#pragma unroll
            for (int mi = 0; mi < 4; mi++)
#pragma unroll
                for (int ni = 0; ni < 4; ni++)
                    acc[mi][ni] = __builtin_amdgcn_mfma_f32_16x16x32_bf16(a[mi], b[ni], acc[mi][ni], 0, 0, 0);
        }
    }

    // epilogue: scale by row_w -> bf16  (C/D: col=lane&15, row=quad*4+reg)
#pragma unroll
    for (int mi = 0; mi < 4; mi++)
#pragma unroll
        for (int ni = 0; ni < 4; ni++)
#pragma unroll
            for (int r = 0; r < 4; r++) {
                int ml = wm * 64 + mi * 16 + quad * 4 + r;
                int row = row0 + ml;
                if (row < cnt) {
                    float w = row_w[off + row];
                    y_buf[(size_t)(off + row) * HID + h0 + wn * 64 + ni * 16 + l16] =
                        f2bf(acc[mi][ni][r] * w);
                }
            }
}

// ---------------------------------------------------------------- combine
__global__ __launch_bounds__(256) void moe_combine(
    const unsigned short* __restrict__ y_buf, const int* __restrict__ tok_rows,
    float* __restrict__ out)
{
    int gid = blockIdx.x * 256 + threadIdx.x;   // T*H/8 threads
    int t = gid >> 7;
    int c = gid & 127;
    u32x4 a = *(const u32x4*)(y_buf + (size_t)tok_rows[2 * t]     * HID + c * 8);
    u32x4 b = *(const u32x4*)(y_buf + (size_t)tok_rows[2 * t + 1] * HID + c * 8);
    float res[8];
#pragma unroll
    for (int j = 0; j < 4; j++) {
        unsigned int wa = a[j], wb = b[j];
        res[2 * j]     = __builtin_bit_cast(float, wa << 16)
                       + __builtin_bit_cast(float, wb << 16);
        res[2 * j + 1] = __builtin_bit_cast(float, wa & 0xffff0000u)
                       + __builtin_bit_cast(float, wb & 0xffff0000u);
    }
    float* o = out + (size_t)t * HID + c * 8;
    *(float4*)(o)     = make_float4(res[0], res[1], res[2], res[3]);
    *(float4*)(o + 4) = make_float4(res[4], res[5], res[6], res[7]);
}

// ---------------------------------------------------------------- launch
extern "C" void kernel_launch(void* const* d_in, const int* in_sizes, int n_in,
                              void* d_out, int out_size, void* d_ws, size_t ws_size,
                              hipStream_t stream)
{
    const float* x      = (const float*)d_in[0];
    const float* gate_w = (const float*)d_in[1];
    const float* w_gate = (const float*)d_in[2];
    const float* w_up   = (const float*)d_in[3];
    const float* w_down = (const float*)d_in[4];
    float* out = (float*)d_out;                    // final [T,H] ++ logits [T,E]
    float* logits_out = out + (size_t)T_TOK * HID;

    char* ws = (char*)d_ws;
    int*   offsets    = (int*)(ws + 0);                  // 9 ints
    int*   n_wl256    = (int*)(ws + 64);
    int*   n_wl128    = (int*)(ws + 68);
    int*   wl256      = (int*)(ws + 128);                // 72 ints
    int*   wl128      = (int*)(ws + 512);                // 144 ints
    int*   hist_g     = (int*)(ws + 2048);               // RBLK*NE = 8 KB
    int*   block_base = (int*)(ws + 2048 + 8192);        // 8 KB
    int*   topk_idx   = (int*)(ws + 32768);                       // 64 KB
    float* topk_w     = (float*)(ws + 32768 + 65536);             // 64 KB
    int*   row_token  = (int*)(ws + 32768 + 2 * 65536);           // 64 KB
    float* row_w      = (float*)(ws + 32768 + 3 * 65536);         // 64 KB
    int*   tok_rows   = (int*)(ws + 32768 + 4 * 65536);           // 64 KB
    size_t o = 32768 + 5 * (size_t)65536 + 32768;        // 393216
    unsigned short* xb   = (unsigned short*)(ws + o); o += (size_t)T_TOK * HID * 2;
    unsigned short* wg_t = (unsigned short*)(ws + o); o += (size_t)NE * INTER * HID * 2;
    unsigned short* wu_t = (unsigned short*)(ws + o); o += (size_t)NE * INTER * HID * 2;
    unsigned short* wd_t = (unsigned short*)(ws + o); o += (size_t)NE * HID * INTER * 2;
    unsigned short* h_buf = (unsigned short*)(ws + o); o += (size_t)NROWS * INTER * 2;
    unsigned short* y_buf = (unsigned short*)(ws + o); o += (size_t)NROWS * HID * 2;

    moe_pre<<<RBLK + NTRT, 256, 0, stream>>>(
        x, gate_w, w_gate, w_up, w_down,
        xb, logits_out, topk_idx, topk_w, hist_g, wg_t, wu_t, wd_t);
    moe_scan<<<1, 256, 0, stream>>>(hist_g, offsets, block_base,
                                    wl256, n_wl256, wl128, n_wl128);
    moe_scatter<<<RBLK, 64, 0, stream>>>(topk_idx, topk_w, block_base,
                                         row_token, row_w, tok_rows);

    moe_gemm1<<<dim3(GX1, MAXWL256), 512, 0, stream>>>(
        xb, wg_t, wu_t, offsets, row_token, wl256, n_wl256, h_buf);
    moe_gemm2<<<dim3(GX2, MAXWL128), 256, 0, stream>>>(
        h_buf, wd_t, offsets, row_w, wl128, n_wl128, y_buf);
    moe_combine<<<(T_TOK * HID / 8) / 256, 256, 0, stream>>>(y_buf, tok_rows, out);
}